// Round 6
// baseline (1116.552 us; speedup 1.0000x reference)
//
#include <hip/hip_runtime.h>
#include <cstdint>
#include <cstddef>
#include <math.h>

#define KNN 7

using short8  = __attribute__((ext_vector_type(8))) short;
using floatx4 = __attribute__((ext_vector_type(4))) float;

// ---------------- workspace layout (in floats) ----------------
static const size_t OFF_ARENA = 0;          // 10,240,000  patch hi/lo bf16 / split-K partials / U / inner0
static const size_t OFF_XS0   = 10240000;   // 10,240,000
static const size_t OFF_XS1   = 20480000;   //  2,560,000
static const size_t OFF_LAST  = 23040000;   //  2,560,000  score (GNN) / last (FPN)
static const size_t OFF_EMB   = 25600000;   //    409,600  emb fp32 / emb2 hi+lo bf16 after fc2
static const size_t OFF_EMB2  = 26009600;   //    409,600
static const size_t OFF_XL    = 26419200;   //  6,553,600 xlr / hilo-splitK part / FPN bf16 img
static const size_t OFF_H1    = 32972800;   //  3,276,800
static const size_t OFF_XL2   = 36249600;   //    819,200 (xlr2)
static const size_t OFF_CAT   = 37068800;   //    819,200
static const size_t OFF_HC    = 37888000;   //    409,600
static const size_t OFF_SRCF  = 38400000;   //     11,200 ints
static const size_t OFF_SRCS  = 38411200;   //     11,200 ints
static const size_t OFF_BF_A  = 38422400;   //  1,700,000 floats = 3.4M bf16 (A casts / conv1 W hi+lo)
static const size_t OFF_BF_W  = 40122400;   //    850,000 floats = 1.7M bf16 (W casts)
// total ~164 MB

static __device__ __forceinline__ unsigned short f2bf(float f) {
    union { float f; unsigned u; } v; v.f = f;
    unsigned u = v.u;
    unsigned r = u + 0x7fffu + ((u >> 16) & 1u);   // RNE
    return (unsigned short)(r >> 16);
}

static __device__ __forceinline__ float bf2f(unsigned short h) {
    union { unsigned u; float f; } v; v.u = ((unsigned)h) << 16; return v.f;
}

// async global->LDS, 16B per lane. LDS dest is wave-uniform base + lane*16.
static __device__ __forceinline__ void glds16(const void* g, void* l) {
    __builtin_amdgcn_global_load_lds((const __attribute__((address_space(1))) void*)g,
                                     (__attribute__((address_space(3))) void*)l, 16, 0, 0);
}

// ============================ fp32 tiled GEMM (NT; exact path) ============
template<int ACT, bool BIAS>
__global__ __launch_bounds__(256)
void gemm_k(const float* __restrict__ A, const float* __restrict__ B,
            const float* __restrict__ bias, float* __restrict__ C, int M, int N, int K)
{
    __shared__ float As[16][68];
    __shared__ float Bs[16][68];
    const int tid = threadIdx.x;
    const int bm0 = blockIdx.y * 64;
    const int bn0 = blockIdx.x * 64;
    const int tx = tid & 15, ty = tid >> 4;
    const int lrow = tid >> 2;
    const int lk4  = (tid & 3) << 2;
    const int m = bm0 + lrow;
    const int nn = bn0 + lrow;
    const bool aok = m < M, bok = nn < N;
    float acc[4][4] = {{0.f,0.f,0.f,0.f},{0.f,0.f,0.f,0.f},{0.f,0.f,0.f,0.f},{0.f,0.f,0.f,0.f}};

    float4 va = {0.f,0.f,0.f,0.f}, vb = {0.f,0.f,0.f,0.f};
    if (aok) va = *(const float4*)(A + (size_t)m * K + lk4);
    if (bok) vb = *(const float4*)(B + (size_t)nn * K + lk4);

    for (int k0 = 0; k0 < K; k0 += 16) {
        As[lk4+0][lrow]=va.x; As[lk4+1][lrow]=va.y; As[lk4+2][lrow]=va.z; As[lk4+3][lrow]=va.w;
        Bs[lk4+0][lrow]=vb.x; Bs[lk4+1][lrow]=vb.y; Bs[lk4+2][lrow]=vb.z; Bs[lk4+3][lrow]=vb.w;
        __syncthreads();
        float4 na = {0.f,0.f,0.f,0.f}, nb = {0.f,0.f,0.f,0.f};
        const bool more = (k0 + 16) < K;
        if (more) {
            if (aok) na = *(const float4*)(A + (size_t)m * K + (k0 + 16 + lk4));
            if (bok) nb = *(const float4*)(B + (size_t)nn * K + (k0 + 16 + lk4));
        }
        #pragma unroll
        for (int k = 0; k < 16; k++) {
            const float4 av = *(const float4*)&As[k][ty << 2];
            const float4 bv = *(const float4*)&Bs[k][tx << 2];
            const float a0=av.x,a1=av.y,a2=av.z,a3=av.w;
            const float b0=bv.x,b1=bv.y,b2=bv.z,b3=bv.w;
            acc[0][0]=fmaf(a0,b0,acc[0][0]); acc[0][1]=fmaf(a0,b1,acc[0][1]);
            acc[0][2]=fmaf(a0,b2,acc[0][2]); acc[0][3]=fmaf(a0,b3,acc[0][3]);
            acc[1][0]=fmaf(a1,b0,acc[1][0]); acc[1][1]=fmaf(a1,b1,acc[1][1]);
            acc[1][2]=fmaf(a1,b2,acc[1][2]); acc[1][3]=fmaf(a1,b3,acc[1][3]);
            acc[2][0]=fmaf(a2,b0,acc[2][0]); acc[2][1]=fmaf(a2,b1,acc[2][1]);
            acc[2][2]=fmaf(a2,b2,acc[2][2]); acc[2][3]=fmaf(a2,b3,acc[2][3]);
            acc[3][0]=fmaf(a3,b0,acc[3][0]); acc[3][1]=fmaf(a3,b1,acc[3][1]);
            acc[3][2]=fmaf(a3,b2,acc[3][2]); acc[3][3]=fmaf(a3,b3,acc[3][3]);
        }
        __syncthreads();
        va = na; vb = nb;
    }
    #pragma unroll
    for (int i = 0; i < 4; i++) {
        const int mm = bm0 + (ty << 2) + i;
        if (mm >= M) continue;
        #pragma unroll
        for (int jj = 0; jj < 4; jj++) {
            const int nc = bn0 + (tx << 2) + jj;
            if (nc >= N) continue;
            float v = acc[i][jj];
            if (BIAS) v += bias[nc];
            if (ACT == 1) v = fmaxf(v, 0.f);
            C[(size_t)mm * N + nc] = v;
        }
    }
}

template<int ACT, bool BIAS>
static inline void gemm32(hipStream_t s, const float* A, const float* B, const float* bias,
                          float* C, int M, int N, int K)
{
    dim3 g((N + 63) / 64, (M + 63) / 64);
    gemm_k<ACT, BIAS><<<g, dim3(256), 0, s>>>(A, B, bias, C, M, N, K);
}

// ============================ bf16 MFMA GEMM ======
// Hybrid pipelines (both counted-vmcnt, both-sides swizzle, glds-staged):
//  - BT_NT:    BK=64, 2 LDS buffers (64 KB), vmcnt(8), stage after barrier-2.
//  - BT_CONV2: BK=32, 3 LDS buffers (48 KB -> 3 blocks/CU), vmcnt(4),
//              stage-before-compute (2-phase prefetch slack). Proven 77us.
// BT_CONV2: 3x3 SAME conv; B = ZERO-PADDED bf16 image [(imH+2)(imW+2)][256];
//           A = weights [O][j*256+c]. Border taps read zeros from the ring.
// OOB rows CLAMPED (not zero-filled): epilogue never writes OOB rows/cols.
enum { BT_NT = 0, BT_CONV2 = 2 };

template<int BT, int ACT, int BAX, bool ADDMAT>
__global__ __launch_bounds__(256)
void bgemm_k(const unsigned short* __restrict__ A, const unsigned short* __restrict__ B,
             const float* __restrict__ bias, const float* __restrict__ bias2, int nsplit,
             const float* __restrict__ Dmat, int Dld,
             float* __restrict__ C, int M, int N, int K, int imH, int imW)
{
    constexpr int LDS_SH = (BT == BT_CONV2) ? 3 * 4096 : 2 * 8192;
    __shared__ unsigned short As[LDS_SH];
    __shared__ unsigned short Bs[LDS_SH];
    const int tid  = threadIdx.x;
    const int lane = tid & 63;
    const int wid  = tid >> 6;
    const int quad = lane >> 4;
    const int l15  = lane & 15;
    const int wy = wid >> 1, wx = wid & 1;

    // block-id swizzle (gridDim.y==2 shapes: conv + 1x1): XCD-chunked bijective,
    // M-pair adjacent -> both M-tiles of a strip share one XCD's L2.
    int bxx = blockIdx.x, byy = blockIdx.y;
    if (gridDim.y == 2) {
        const int nbx = gridDim.x;
        const int nwg = nbx * 2;
        const int hw  = byy * nbx + bxx;
        const int q = nwg >> 3, r = nwg & 7;
        const int x8 = hw & 7, d = hw >> 3;
        const int lg = (x8 < r) ? x8 * (q + 1) + d : r * (q + 1) + (x8 - r) * q + d;
        byy = lg & 1; bxx = lg >> 1;
    }
    const int bm0 = byy * 128;
    const int bn0 = bxx * 128;

    floatx4 zero = {0.f, 0.f, 0.f, 0.f};
    floatx4 acc[4][4];
    #pragma unroll
    for (int i = 0; i < 4; i++)
        #pragma unroll
        for (int j = 0; j < 4; j++) acc[i][j] = zero;

    if constexpr (BT == BT_CONV2) {
        // ---------- BK=32, 3-buffer pipeline ----------
        const int l4 = lane >> 2;
        const int swc = (((lane & 3) ^ ((lane >> 3) & 3)) << 3);   // shorts
        const int r0 = wid * 32 + l4;
        const int r1 = r0 + 16;
        int am0 = bm0 + r0; if (am0 > M - 1) am0 = M - 1;
        int am1 = bm0 + r1; if (am1 > M - 1) am1 = M - 1;
        const unsigned short* aP0 = A + (size_t)am0 * K + swc;
        const unsigned short* aP1 = A + (size_t)am1 * K + swc;
        const int W2 = imW + 2;
        int pp0 = bn0 + r0; if (pp0 > N - 1) pp0 = N - 1;
        int pp1 = bn0 + r1; if (pp1 > N - 1) pp1 = N - 1;
        const int py0 = pp0 / imW, px0 = pp0 - py0 * imW;
        const int py1 = pp1 / imW, px1 = pp1 - py1 * imW;
        const unsigned short* bP0 = B + ((size_t)(py0 + 1) * W2 + px0 + 1) * 256 + swc;
        const unsigned short* bP1 = B + ((size_t)(py1 + 1) * W2 + px1 + 1) * 256 + swc;

        auto stage = [&](int buf, int t) {
            const int k0 = t << 5;
            glds16(aP0 + k0, &As[buf * 4096 + wid * 1024]);
            glds16(aP1 + k0, &As[buf * 4096 + wid * 1024 + 512]);
            const int jj = k0 >> 8;              // tap 0..8 (uniform scalar)
            const int j3 = jj / 3;
            const ptrdiff_t toff = (ptrdiff_t)((j3 - 1) * W2 + (jj - j3 * 3 - 1)) * 256
                                 + (k0 & 255);
            glds16(bP0 + toff, &Bs[buf * 4096 + wid * 1024]);
            glds16(bP1 + toff, &Bs[buf * 4096 + wid * 1024 + 512]);
        };
        const int rsw = ((quad ^ ((l15 >> 1) & 3)) << 3);   // shorts
        auto compute = [&](int buf) {
            short8 af[4], bfr[4];
            #pragma unroll
            for (int i = 0; i < 4; i++)
                af[i] = *(const short8*)&As[buf * 4096 + (wy * 64 + i * 16 + l15) * 32 + rsw];
            #pragma unroll
            for (int j = 0; j < 4; j++)
                bfr[j] = *(const short8*)&Bs[buf * 4096 + (wx * 64 + j * 16 + l15) * 32 + rsw];
            #pragma unroll
            for (int i = 0; i < 4; i++)
                #pragma unroll
                for (int j = 0; j < 4; j++)
                    acc[i][j] = __builtin_amdgcn_mfma_f32_16x16x32_bf16(af[i], bfr[j], acc[i][j], 0, 0, 0);
        };

        const int T = K >> 5;
        stage(0, 0);
        if (T > 1) stage(1, 1);
        int cb = 0, sb = 2;
        for (int t = 0; t < T; t++) {
            if (t < T - 1) asm volatile("s_waitcnt vmcnt(4) lgkmcnt(0)" ::: "memory");
            else           asm volatile("s_waitcnt vmcnt(0) lgkmcnt(0)" ::: "memory");
            __builtin_amdgcn_s_barrier();
            __builtin_amdgcn_sched_barrier(0);
            if (t + 2 < T) stage(sb, t + 2);
            compute(cb);
            cb = (cb == 2) ? 0 : cb + 1;
            sb = (sb == 2) ? 0 : sb + 1;
        }
    } else {
        // ---------- BK=64, 2-buffer pipeline ----------
        const int l8 = lane >> 3;
        const int swq = (((lane & 7) ^ (l8 & 7)) << 3);   // swizzled source chunk
        const unsigned short* aP[4];
        const unsigned short* bP[4];
        #pragma unroll
        for (int g = 0; g < 4; g++) {
            int ra = bm0 + wid * 32 + g * 8 + l8;
            if (ra > M - 1) ra = M - 1;
            aP[g] = A + (size_t)ra * K + swq;
            int rb = bn0 + wid * 32 + g * 8 + l8;
            if (rb > N - 1) rb = N - 1;
            bP[g] = B + (size_t)rb * K + swq;
        }

        auto stage = [&](int buf, int t) {
            const int k0 = t << 6;
            #pragma unroll
            for (int g = 0; g < 4; g++)
                glds16(aP[g] + k0, &As[buf * 8192 + wid * 2048 + g * 512]);
            #pragma unroll
            for (int g = 0; g < 4; g++)
                glds16(bP[g] + k0, &Bs[buf * 8192 + wid * 2048 + g * 512]);
        };
        auto compute = [&](int buf) {
            #pragma unroll
            for (int ks = 0; ks < 2; ks++) {
                short8 af[4], bfr[4];
                #pragma unroll
                for (int i = 0; i < 4; i++)
                    af[i] = *(const short8*)&As[buf * 8192 + (wy * 64 + i * 16 + l15) * 64
                                                + (((ks * 4 + quad) ^ (l15 & 7)) << 3)];
                #pragma unroll
                for (int j = 0; j < 4; j++)
                    bfr[j] = *(const short8*)&Bs[buf * 8192 + (wx * 64 + j * 16 + l15) * 64
                                                 + (((ks * 4 + quad) ^ (l15 & 7)) << 3)];
                #pragma unroll
                for (int i = 0; i < 4; i++)
                    #pragma unroll
                    for (int j = 0; j < 4; j++)
                        acc[i][j] = __builtin_amdgcn_mfma_f32_16x16x32_bf16(af[i], bfr[j], acc[i][j], 0, 0, 0);
            }
        };

        const int T2 = K >> 6;
        stage(0, 0);
        if (T2 > 1) stage(1, 1);
        for (int t = 0; t < T2; t++) {
            if (t + 1 < T2) asm volatile("s_waitcnt vmcnt(8) lgkmcnt(0)" ::: "memory");
            else            asm volatile("s_waitcnt vmcnt(0) lgkmcnt(0)" ::: "memory");
            __builtin_amdgcn_s_barrier();
            __builtin_amdgcn_sched_barrier(0);
            compute(t & 1);
            __builtin_amdgcn_s_barrier();
            __builtin_amdgcn_sched_barrier(0);
            if (t + 2 < T2) stage(t & 1, t + 2);
        }
    }

    #pragma unroll
    for (int i = 0; i < 4; i++) {
        #pragma unroll
        for (int r = 0; r < 4; r++) {
            const int m = bm0 + wy * 64 + i * 16 + quad * 4 + r;
            if (m >= M) continue;
            #pragma unroll
            for (int j = 0; j < 4; j++) {
                const int n = bn0 + wx * 64 + j * 16 + l15;
                if (n >= N) continue;
                float v = acc[i][j][r];
                if (bias != nullptr)
                    v += (BAX == 0) ? bias[m] : (n < nsplit ? bias[n] : bias2[n - nsplit]);
                if (ACT == 1) v = fmaxf(v, 0.f);
                if (ADDMAT) v += Dmat[(size_t)m * Dld + n];
                C[(size_t)m * N + n] = v;
            }
        }
    }
}

template<int BT, int ACT, int BAX, bool ADDMAT>
static inline void bgemm(hipStream_t s, const unsigned short* A, const unsigned short* B,
                         const float* bias, const float* bias2, int nsplit,
                         const float* D, int Dld, float* C,
                         int M, int N, int K, int imH = 0, int imW = 0)
{
    dim3 g((N + 127) / 128, (M + 127) / 128);
    bgemm_k<BT, ACT, BAX, ADDMAT><<<g, dim3(256), 0, s>>>(A, B, bias, bias2, nsplit,
                                                          D, Dld, C, M, N, K, imH, imW);
}

// ---- bf16 split-K (NT only): partials fp32; BK=64 pipeline ----
__global__ __launch_bounds__(256)
void bgemm_sk_k(const unsigned short* __restrict__ A, const unsigned short* __restrict__ B,
                float* __restrict__ part, int M, int N, int K, int Kc)
{
    __shared__ unsigned short As[2][8192];
    __shared__ unsigned short Bs[2][8192];
    const int tid  = threadIdx.x;
    const int lane = tid & 63;
    const int wid  = tid >> 6;
    const int quad = lane >> 4;
    const int l15  = lane & 15;
    const int l8   = lane >> 3;
    const int wy = wid >> 1, wx = wid & 1;
    const int bm0 = blockIdx.y * 128;
    const int bn0 = blockIdx.x * 128;
    const int kbeg = blockIdx.z * Kc;
    const int kend = (kbeg + Kc < K) ? kbeg + Kc : K;

    floatx4 zero = {0.f, 0.f, 0.f, 0.f};
    floatx4 acc[4][4];
    #pragma unroll
    for (int i = 0; i < 4; i++)
        #pragma unroll
        for (int j = 0; j < 4; j++) acc[i][j] = zero;

    const int swq = (((lane & 7) ^ (l8 & 7)) << 3);
    const unsigned short* aP[4];
    const unsigned short* bP[4];
    #pragma unroll
    for (int g = 0; g < 4; g++) {
        int ra = bm0 + wid * 32 + g * 8 + l8;
        if (ra > M - 1) ra = M - 1;
        aP[g] = A + (size_t)ra * K + kbeg + swq;
        int rb = bn0 + wid * 32 + g * 8 + l8;
        if (rb > N - 1) rb = N - 1;
        bP[g] = B + (size_t)rb * K + kbeg + swq;
    }

    auto stage = [&](int buf, int t) {
        const int k0 = t << 6;
        #pragma unroll
        for (int g = 0; g < 4; g++)
            glds16(aP[g] + k0, &As[buf][wid * 2048 + g * 512]);
        #pragma unroll
        for (int g = 0; g < 4; g++)
            glds16(bP[g] + k0, &Bs[buf][wid * 2048 + g * 512]);
    };
    auto compute = [&](int buf) {
        #pragma unroll
        for (int ks = 0; ks < 2; ks++) {
            short8 af[4], bfr[4];
            #pragma unroll
            for (int i = 0; i < 4; i++)
                af[i] = *(const short8*)&As[buf][(wy * 64 + i * 16 + l15) * 64
                                                 + (((ks * 4 + quad) ^ (l15 & 7)) << 3)];
            #pragma unroll
            for (int j = 0; j < 4; j++)
                bfr[j] = *(const short8*)&Bs[buf][(wx * 64 + j * 16 + l15) * 64
                                                  + (((ks * 4 + quad) ^ (l15 & 7)) << 3)];
            #pragma unroll
            for (int i = 0; i < 4; i++)
                #pragma unroll
                for (int j = 0; j < 4; j++)
                    acc[i][j] = __builtin_amdgcn_mfma_f32_16x16x32_bf16(af[i], bfr[j], acc[i][j], 0, 0, 0);
        }
    };

    const int T2 = (kend - kbeg) >> 6;
    stage(0, 0);
    if (T2 > 1) stage(1, 1);
    for (int t = 0; t < T2; t++) {
        if (t + 1 < T2) asm volatile("s_waitcnt vmcnt(8) lgkmcnt(0)" ::: "memory");
        else            asm volatile("s_waitcnt vmcnt(0) lgkmcnt(0)" ::: "memory");
        __builtin_amdgcn_s_barrier();
        __builtin_amdgcn_sched_barrier(0);
        compute(t & 1);
        __builtin_amdgcn_s_barrier();
        __builtin_amdgcn_sched_barrier(0);
        if (t + 2 < T2) stage(t & 1, t + 2);
    }

    float* P = part + (size_t)blockIdx.z * M * N;
    #pragma unroll
    for (int i = 0; i < 4; i++) {
        #pragma unroll
        for (int r = 0; r < 4; r++) {
            const int m = bm0 + wy * 64 + i * 16 + quad * 4 + r;
            if (m >= M) continue;
            #pragma unroll
            for (int j = 0; j < 4; j++) {
                const int n = bn0 + wx * 64 + j * 16 + l15;
                if (n >= N) continue;
                P[(size_t)m * N + n] = acc[i][j][r];
            }
        }
    }
}

// ---- split-precision (hi/lo bf16) fp32-emulating split-K GEMM ----
// C = A*B as Ahi*Bhi + Alo*Bhi + Ahi*Blo (missing lo*lo ~ 2^-18).
// blockIdx.z = seg * S3 + slab. Slab lengths must be %64 == 0.
__global__ __launch_bounds__(256)
void bgemm_hilo_sk_k(const unsigned short* __restrict__ Ahi, const unsigned short* __restrict__ Alo,
                     const unsigned short* __restrict__ Bhi, const unsigned short* __restrict__ Blo,
                     float* __restrict__ part, int M, int N, int K, int Kc, int S3)
{
    __shared__ unsigned short As[2][8192];
    __shared__ unsigned short Bs[2][8192];
    const int tid  = threadIdx.x;
    const int lane = tid & 63;
    const int wid  = tid >> 6;
    const int quad = lane >> 4;
    const int l15  = lane & 15;
    const int l8   = lane >> 3;
    const int wy = wid >> 1, wx = wid & 1;
    const int bm0 = blockIdx.y * 128;
    const int bn0 = blockIdx.x * 128;

    const int seg  = blockIdx.z / S3;
    const int slab = blockIdx.z - seg * S3;
    const unsigned short* A = (seg == 1) ? Alo : Ahi;
    const unsigned short* B = (seg == 2) ? Blo : Bhi;
    const int kbeg = slab * Kc;
    const int kend = (kbeg + Kc < K) ? kbeg + Kc : K;

    floatx4 zero = {0.f, 0.f, 0.f, 0.f};
    floatx4 acc[4][4];
    #pragma unroll
    for (int i = 0; i < 4; i++)
        #pragma unroll
        for (int j = 0; j < 4; j++) acc[i][j] = zero;

    const int swq = (((lane & 7) ^ (l8 & 7)) << 3);
    const unsigned short* aP[4];
    const unsigned short* bP[4];
    #pragma unroll
    for (int g = 0; g < 4; g++) {
        int ra = bm0 + wid * 32 + g * 8 + l8;
        if (ra > M - 1) ra = M - 1;
        aP[g] = A + (size_t)ra * K + kbeg + swq;
        int rb = bn0 + wid * 32 + g * 8 + l8;
        if (rb > N - 1) rb = N - 1;
        bP[g] = B + (size_t)rb * K + kbeg + swq;
    }

    auto stage = [&](int buf, int t) {
        const int k0 = t << 6;
        #pragma unroll
        for (int g = 0; g < 4; g++)
            glds16(aP[g] + k0, &As[buf][wid * 2048 + g * 512]);
        #pragma unroll
        for (int g = 0; g < 4; g++)
            glds16(bP[g] + k0, &Bs[buf][wid * 2048 + g * 512]);
    };
    auto compute = [&](int buf) {
        #pragma unroll
        for (int ks = 0; ks < 2; ks++) {
            short8 af[4], bfr[4];
            #pragma unroll
            for (int i = 0; i < 4; i++)
                af[i] = *(const short8*)&As[buf][(wy * 64 + i * 16 + l15) * 64
                                                 + (((ks * 4 + quad) ^ (l15 & 7)) << 3)];
            #pragma unroll
            for (int j = 0; j < 4; j++)
                bfr[j] = *(const short8*)&Bs[buf][(wx * 64 + j * 16 + l15) * 64
                                                  + (((ks * 4 + quad) ^ (l15 & 7)) << 3)];
            #pragma unroll
            for (int i = 0; i < 4; i++)
                #pragma unroll
                for (int j = 0; j < 4; j++)
                    acc[i][j] = __builtin_amdgcn_mfma_f32_16x16x32_bf16(af[i], bfr[j], acc[i][j], 0, 0, 0);
        }
    };

    const int T2 = (kend - kbeg) >> 6;
    stage(0, 0);
    if (T2 > 1) stage(1, 1);
    for (int t = 0; t < T2; t++) {
        if (t + 1 < T2) asm volatile("s_waitcnt vmcnt(8) lgkmcnt(0)" ::: "memory");
        else            asm volatile("s_waitcnt vmcnt(0) lgkmcnt(0)" ::: "memory");
        __builtin_amdgcn_s_barrier();
        __builtin_amdgcn_sched_barrier(0);
        compute(t & 1);
        __builtin_amdgcn_s_barrier();
        __builtin_amdgcn_sched_barrier(0);
        if (t + 2 < T2) stage(t & 1, t + 2);
    }

    float* P = part + (size_t)blockIdx.z * M * N;
    #pragma unroll
    for (int i = 0; i < 4; i++) {
        #pragma unroll
        for (int r = 0; r < 4; r++) {
            const int m = bm0 + wy * 64 + i * 16 + quad * 4 + r;
            if (m >= M) continue;
            #pragma unroll
            for (int j = 0; j < 4; j++) {
                const int n = bn0 + wx * 64 + j * 16 + l15;
                if (n >= N) continue;
                P[(size_t)m * N + n] = acc[i][j][r];
            }
        }
    }
}

// reduce S slabs + optional dual-bias(axis n) + relu + addmat
template<int ACT, bool ADDMAT, bool BIAS = true>
__global__ void bsk_reduce_k(const float* __restrict__ part,
                             const float* __restrict__ bias, const float* __restrict__ bias2,
                             int nsplit, const float* __restrict__ Dmat, int Dld,
                             float* __restrict__ C, int MN, int N, int S)
{
    const int i4 = (blockIdx.x * 256 + threadIdx.x) * 4;
    if (i4 >= MN) return;
    float4 a = *(const float4*)(part + i4);
    for (int s = 1; s < S; s++) {
        const float4 b = *(const float4*)(part + (size_t)s * MN + i4);
        a.x += b.x; a.y += b.y; a.z += b.z; a.w += b.w;
    }
    const int n = i4 % N;
    if (BIAS) {
        const float* bb = (n < nsplit) ? (bias + n) : (bias2 + n - nsplit);
        a.x += bb[0]; a.y += bb[1]; a.z += bb[2]; a.w += bb[3];
    }
    if (ACT == 1) {
        a.x = fmaxf(a.x, 0.f); a.y = fmaxf(a.y, 0.f);
        a.z = fmaxf(a.z, 0.f); a.w = fmaxf(a.w, 0.f);
    }
    if (ADDMAT) {
        const int m = i4 / N;
        const float4 d = *(const float4*)(Dmat + (size_t)m * Dld + n);
        a.x += d.x; a.y += d.y; a.z += d.z; a.w += d.w;
    }
    *(float4*)(C + i4) = a;
}

template<int ACT, bool ADDMAT>
static inline void bgemm_sk(hipStream_t s, const unsigned short* A, const unsigned short* B,
                            const float* bias, const float* bias2, int nsplit,
                            const float* D, int Dld, float* C, float* part,
                            int M, int N, int K, int S)
{
    const int Kc = ((K / S + 63) / 64) * 64;
    dim3 g((N + 127) / 128, (M + 127) / 128, S);
    bgemm_sk_k<<<g, dim3(256), 0, s>>>(A, B, part, M, N, K, Kc);
    const int MN = M * N;
    bsk_reduce_k<ACT, ADDMAT><<<dim3((MN / 4 + 255) / 256), dim3(256), 0, s>>>(
        part, bias, bias2, nsplit, D, Dld, C, MN, N, S);
}

// ============================ cast / reorder kernels ============================
__global__ void cast_bf16_k(const float* __restrict__ in, unsigned short* __restrict__ out, int total)
{
    const int i4 = (blockIdx.x * 256 + threadIdx.x) * 4;
    if (i4 + 4 <= total) {
        const float4 v = *(const float4*)(in + i4);
        ushort4 o;
        o.x = f2bf(v.x); o.y = f2bf(v.y); o.z = f2bf(v.z); o.w = f2bf(v.w);
        *(ushort4*)(out + i4) = o;
    } else {
        for (int i = i4; i < total; i++) out[i] = f2bf(in[i]);
    }
}

static inline void cast_bf(hipStream_t s, const float* in, unsigned short* out, int total)
{
    cast_bf16_k<<<dim3((total / 4 + 255) / 256), dim3(256), 0, s>>>(in, out, total);
}

// elementwise hi/lo split cast
__global__ void cast_hilo_k(const float* __restrict__ in, unsigned short* __restrict__ hi,
                            unsigned short* __restrict__ lo, int total)
{
    const int i4 = (blockIdx.x * 256 + threadIdx.x) * 4;
    if (i4 + 4 <= total) {
        const float4 v = *(const float4*)(in + i4);
        ushort4 h, l;
        h.x = f2bf(v.x); l.x = f2bf(v.x - bf2f(h.x));
        h.y = f2bf(v.y); l.y = f2bf(v.y - bf2f(h.y));
        h.z = f2bf(v.z); l.z = f2bf(v.z - bf2f(h.z));
        h.w = f2bf(v.w); l.w = f2bf(v.w - bf2f(h.w));
        *(ushort4*)(hi + i4) = h;
        *(ushort4*)(lo + i4) = l;
    } else {
        for (int i = i4; i < total; i++) {
            unsigned short h = f2bf(in[i]);
            hi[i] = h; lo[i] = f2bf(in[i] - bf2f(h));
        }
    }
}

__device__ __forceinline__ void cast_t_body(const float* __restrict__ in,
                                            unsigned short* __restrict__ out, int K, int N)
{
    __shared__ float tile[64][65];
    const int n0 = blockIdx.x * 64;
    const int k0 = blockIdx.y * 64;
    const int t = threadIdx.x;
    const int r = t >> 2;
    const int c4 = (t & 3) << 4;
    {
        const int k = k0 + r;
        if (k < K && n0 + c4 + 16 <= N) {
            const float4* p = (const float4*)(in + (size_t)k * N + n0 + c4);
            *(float4*)&tile[r][c4]      = p[0];
            *(float4*)&tile[r][c4 + 4]  = p[1];
            *(float4*)&tile[r][c4 + 8]  = p[2];
            *(float4*)&tile[r][c4 + 12] = p[3];
        } else {
            for (int i = 0; i < 16; i++)
                tile[r][c4 + i] = (k < K && n0 + c4 + i < N) ? in[(size_t)k * N + n0 + c4 + i] : 0.f;
        }
    }
    __syncthreads();
    const int n = n0 + r;
    if (n >= N) return;
    unsigned short tmp[16];
    #pragma unroll
    for (int i = 0; i < 16; i++) tmp[i] = f2bf(tile[c4 + i][r]);
    if (k0 + 64 <= K) {
        *(uint4*)(out + (size_t)n * K + k0 + c4)     = *(uint4*)&tmp[0];
        *(uint4*)(out + (size_t)n * K + k0 + c4 + 8) = *(uint4*)&tmp[8];
    } else {
        for (int i = 0; i < 16; i++)
            if (k0 + c4 + i < K) out[(size_t)n * K + k0 + c4 + i] = tmp[i];
    }
}

__global__ void cast_t_k(const float* __restrict__ in, unsigned short* __restrict__ out, int K, int N)
{
    cast_t_body(in, out, K, N);
}

__global__ void cast_t2_k(const float* __restrict__ in0, const float* __restrict__ in1,
                          unsigned short* __restrict__ out0, unsigned short* __restrict__ out1,
                          int K, int N)
{
    if (blockIdx.z == 0) cast_t_body(in0, out0, K, N);
    else                 cast_t_body(in1, out1, K, N);
}

static inline void cast_t(hipStream_t s, const float* in, unsigned short* out, int K, int N)
{
    cast_t_k<<<dim3((N + 63) / 64, (K + 63) / 64), dim3(256), 0, s>>>(in, out, K, N);
}

static inline void cast_t2(hipStream_t s, const float* in0, const float* in1,
                           unsigned short* out0, unsigned short* out1, int K, int N)
{
    cast_t2_k<<<dim3((N + 63) / 64, (K + 63) / 64, 2), dim3(256), 0, s>>>(in0, in1, out0, out1, K, N);
}

// transpose-cast [256][N] fp32 -> ZERO-PADDED bf16 image [(imH+2)(imW+2)][256]
// optional fused nearest-2x upsample-add: + up[c][py>>1][px>>1] (up is [256][upW][upW])
__global__ void cast_t_pad_k(const float* __restrict__ in, const float* __restrict__ up,
                             unsigned short* __restrict__ out, int N, int imW, int upW)
{
    __shared__ float tile[64][65];
    const int n0 = blockIdx.x * 64;
    const int k0 = blockIdx.y * 64;   // 0..3 * 64, K = 256
    const int t = threadIdx.x;
    const int r = t >> 2;
    const int c4 = (t & 3) << 4;
    {
        const int k = k0 + r;
        if (n0 + c4 + 16 <= N) {
            const float4* p = (const float4*)(in + (size_t)k * N + n0 + c4);
            *(float4*)&tile[r][c4]      = p[0];
            *(float4*)&tile[r][c4 + 4]  = p[1];
            *(float4*)&tile[r][c4 + 8]  = p[2];
            *(float4*)&tile[r][c4 + 12] = p[3];
        } else {
            for (int i = 0; i < 16; i++)
                tile[r][c4 + i] = (n0 + c4 + i < N) ? in[(size_t)k * N + n0 + c4 + i] : 0.f;
        }
    }
    __syncthreads();
    const int n = n0 + r;
    if (n >= N) return;
    const int py = n / imW, px = n - py * imW;
    unsigned short tmp[16];
    if (up != nullptr) {
        const float* u = up + (size_t)(py >> 1) * upW + (px >> 1);
        #pragma unroll
        for (int i = 0; i < 16; i++)
            tmp[i] = f2bf(tile[c4 + i][r] + u[(size_t)(k0 + c4 + i) * upW * upW]);
    } else {
        #pragma unroll
        for (int i = 0; i < 16; i++) tmp[i] = f2bf(tile[c4 + i][r]);
    }
    unsigned short* o = out + ((size_t)(py + 1) * (imW + 2) + px + 1) * 256 + k0 + c4;
    *(uint4*)(o)     = *(uint4*)&tmp[0];
    *(uint4*)(o + 8) = *(uint4*)&tmp[8];
}

static inline void cast_t_pad(hipStream_t s, const float* in, const float* up,
                              unsigned short* out, int N, int imW, int upW)
{
    cast_t_pad_k<<<dim3((N + 63) / 64, 4), dim3(256), 0, s>>>(in, up, out, N, imW, upW);
}

// zero the 1-pixel border ring of the padded image
__global__ void zero_ring_k(unsigned short* __restrict__ out, int imH, int imW)
{
    const int W2 = imW + 2;
    const int nb = 2 * W2 + 2 * imH;          // border pixels
    const int idx = blockIdx.x * 256 + threadIdx.x;
    if (idx >= nb * 32) return;               // 32 x 8-short chunks per pixel
    const int p = idx >> 5;
    const int c8 = (idx & 31) << 3;
    int row;
    if (p < W2)            row = p;
    else if (p < 2 * W2)   row = (imH + 1) * W2 + (p - W2);
    else { const int q = p - 2 * W2; const int y = q >> 1;
           row = (y + 1) * W2 + ((q & 1) ? (imW + 1) : 0); }
    *(uint4*)(out + (size_t)row * 256 + c8) = (uint4){0, 0, 0, 0};
}

static inline void zero_ring(hipStream_t s, unsigned short* out, int imH, int imW)
{
    const int tot = (2 * (imW + 2) + 2 * imH) * 32;
    zero_ring_k<<<dim3((tot + 255) / 256), dim3(256), 0, s>>>(out, imH, imW);
}

__global__ void reorder_w3_k(const float* __restrict__ in, unsigned short* __restrict__ out)
{
    const int idx = blockIdx.x * 256 + threadIdx.x;
    if (idx >= 589824) return;
    const int o = idx / 2304;
    const int r = idx - o * 2304;
    const int j = r >> 8;
    const int c = r & 255;
    out[idx] = f2bf(in[(size_t)o * 2304 + c * 9 + j]);
}

// ============================ small kernels ============================
// extract patches directly into hi/lo bf16 A-matrices [n][6400]
__global__ void extract_patches_hilo_k(const float* __restrict__ f,
                                       unsigned short* __restrict__ hi,
                                       unsigned short* __restrict__ lo,
                                       int nw, int H, int total)
{
    int idx = blockIdx.x * 256 + threadIdx.x;
    if (idx >= total) return;
    int q = idx % 6400;
    int p = idx / 6400;
    int c = q / 25;
    int rem = q - c * 25;
    int a = rem / 5, b = rem - (rem / 5) * 5;
    int ih = p / nw, iw = p - (p / nw) * nw;
    const float v = f[(size_t)c * H * H + (size_t)(ih * 5 + a) * H + (iw * 5 + b)];
    const unsigned short h = f2bf(v);
    hi[idx] = h;
    lo[idx] = f2bf(v - bf2f(h));
}

__global__ void topk_feat_k(const float* __restrict__ score, int* __restrict__ srcCols, int n)
{
    const int r = blockIdx.x;
    const int lane = threadIdx.x;
    const float* row = score + (size_t)r * n;
    int   sel[KNN];
    float selv[KNN];
    #pragma unroll
    for (int t = 0; t < KNN; t++) {
        float best = -__builtin_huge_valf();
        int   bidx = 0x7fffffff;
        for (int c = lane; c < n; c += 64) {
            bool taken = false;
            #pragma unroll
            for (int u = 0; u < KNN; u++)
                if (u < t && sel[u] == c) taken = true;
            if (taken) continue;
            float v = row[c];
            if (v > best || (v == best && c < bidx)) { best = v; bidx = c; }
        }
        #pragma unroll
        for (int off = 32; off > 0; off >>= 1) {
            float ov = __shfl_down(best, off);
            int   oi = __shfl_down(bidx, off);
            if (ov > best || (ov == best && oi < bidx)) { best = ov; bidx = oi; }
        }
        best = __shfl(best, 0);
        bidx = __shfl(bidx, 0);
        sel[t] = bidx; selv[t] = best;
    }
    if (lane < KNN) {
        int c = -1; float v = 0.f;
        #pragma unroll
        for (int t = 0; t < KNN; t++)
            if (lane == t) { c = sel[t]; v = selv[t]; }
        srcCols[r * KNN + lane] = (c > r && v != 0.0f) ? c : -1;
    }
}

__global__ void topk_spatial_k(int* __restrict__ srcCols, int n, int nw)
{
    const int r = blockIdx.x;
    const int lane = threadIdx.x;
    const int ri = r / nw, rj = r - (r / nw) * nw;
    int sel[KNN];
    #pragma unroll
    for (int t = 0; t < KNN; t++) {
        int bkey = 0x7fffffff;
        for (int c = lane; c < n; c += 64) {
            bool taken = false;
            #pragma unroll
            for (int u = 0; u < KNN; u++)
                if (u < t && sel[u] == c) taken = true;
            if (taken) continue;
            const int ci = c / nw, cj = c - (c / nw) * nw;
            const int dy = (ri - ci) * 5, dx = (rj - cj) * 5;
            const int d2 = dy * dy + dx * dx;
            const int key = (d2 << 11) | c;
            if (key < bkey) bkey = key;
        }
        #pragma unroll
        for (int off = 32; off > 0; off >>= 1) {
            int ok = __shfl_down(bkey, off);
            if (ok < bkey) bkey = ok;
        }
        bkey = __shfl(bkey, 0);
        sel[t] = bkey & 2047;
    }
    if (lane < KNN) {
        int c = -1;
        #pragma unroll
        for (int t = 0; t < KNN; t++) if (lane == t) c = sel[t];
        srcCols[r * KNN + lane] = (c > r) ? c : -1;
    }
}

// fused GATv2: logits + softmax + aggregate in one kernel.
__global__ void gat_fused_k(const float* __restrict__ x, int xroff, int xstride,
                            const float* __restrict__ att,
                            const int* __restrict__ srcCols, const float* __restrict__ bias,
                            float* __restrict__ out, int n, int H, int ostride, int ooff)
{
    const int wid = (blockIdx.x * blockDim.x + threadIdx.x) >> 6;
    const int lane = threadIdx.x & 63;
    if (wid >= n * H) return;
    const int h = wid % H;
    const int r = wid / H;
    const int d0 = lane << 2;

    const float4 xrf  = *(const float4*)(x + (size_t)r * xstride + xroff + h * 256 + d0);
    const float4 attf = *(const float4*)(att + (size_t)h * 256 + d0);

    int srcs[8];
    #pragma unroll
    for (int s_ = 0; s_ < KNN; s_++) srcs[s_] = srcCols[r * KNN + s_];
    srcs[7] = r;

    float4 xlf[8];
    float  e[8];
    #pragma unroll
    for (int s_ = 0; s_ < 8; s_++) {
        const int c = srcs[s_];
        float4 v = {0.f, 0.f, 0.f, 0.f};
        if (c >= 0) v = *(const float4*)(x + (size_t)c * xstride + h * 256 + d0);
        xlf[s_] = v;
        float m, p = 0.f;
        m = v.x + xrf.x; m = (m > 0.f) ? m : 0.2f * m; p += m * attf.x;
        m = v.y + xrf.y; m = (m > 0.f) ? m : 0.2f * m; p += m * attf.y;
        m = v.z + xrf.z; m = (m > 0.f) ? m : 0.2f * m; p += m * attf.z;
        m = v.w + xrf.w; m = (m > 0.f) ? m : 0.2f * m; p += m * attf.w;
        #pragma unroll
        for (int off = 32; off > 0; off >>= 1) p += __shfl_down(p, off);
        e[s_] = __shfl(p, 0);
    }

    float mx = e[7];
    #pragma unroll
    for (int s_ = 0; s_ < KNN; s_++)
        if (srcs[s_] >= 0) mx = fmaxf(mx, e[s_]);
    float a[8], denom = 0.f;
    #pragma unroll
    for (int s_ = 0; s_ < 8; s_++) {
        a[s_] = (s_ == 7 || srcs[s_] >= 0) ? expf(e[s_] - mx) : 0.f;
        denom += a[s_];
    }
    const float inv = 1.f / (denom + 1e-16f);

    float o0 = 0.f, o1 = 0.f, o2 = 0.f, o3 = 0.f;
    #pragma unroll
    for (int s_ = 0; s_ < 8; s_++) {
        const float al = a[s_] * inv;
        o0 = fmaf(al, xlf[s_].x, o0); o1 = fmaf(al, xlf[s_].y, o1);
        o2 = fmaf(al, xlf[s_].z, o2); o3 = fmaf(al, xlf[s_].w, o3);
    }
    const float* bb = bias + (size_t)h * 256 + d0;
    o0 += bb[0]; o1 += bb[1]; o2 += bb[2]; o3 += bb[3];
    o0 = (o0 > 0.f) ? o0 : (expf(o0) - 1.f);
    o1 = (o1 > 0.f) ? o1 : (expf(o1) - 1.f);
    o2 = (o2 > 0.f) ? o2 : (expf(o2) - 1.f);
    o3 = (o3 > 0.f) ? o3 : (expf(o3) - 1.f);
    float4 res = {o0, o1, o2, o3};
    *(float4*)(out + (size_t)r * ostride + ooff + (size_t)h * 256 + d0) = res;
}

__global__ void scatter_convT_k(const float* __restrict__ f, const float* __restrict__ U,
                                const float* __restrict__ bias, float* __restrict__ xs,
                                int nw, int H, int total)
{
    int idx = blockIdx.x * 256 + threadIdx.x;
    if (idx >= total) return;
    int x = idx % H;
    int t = idx / H;
    int y = t % H;
    int o = t / H;
    int j = y / 5, a = y - j * 5;
    int i = x / 5, b = x - i * 5;
    int p = i * nw + j;
    float v = U[(size_t)p * 6400 + o * 25 + a * 5 + b] + bias[o];
    v = fmaxf(v, 0.f);
    xs[idx] = f[idx] + v;
}

// ============================ orchestration ============================
static void run_level(void* const* d_in, float* ws, int l, int H, hipStream_t s)
{
    const float* f = (const float*)d_in[l];
    const int nh = H / 5, nw = nh, n = nh * nw, HW = H * H;

    const float* convT_w = (const float*)d_in[6]  + (size_t)l * 1638400;
    const float* convT_b = (const float*)d_in[7]  + l * 256;
    const float* conv1_w = (const float*)d_in[8]  + (size_t)l * 1638400;
    const float* conv1_b = (const float*)d_in[9]  + l * 256;
    const float* fc2_w   = (const float*)d_in[10] + (size_t)l * 65536;
    const float* fc2_b   = (const float*)d_in[11] + l * 256;
    const float* fc3_w   = (const float*)d_in[12] + (size_t)l * 131072;
    const float* fc3_b   = (const float*)d_in[13] + l * 256;
    const float* g1_wl   = (const float*)d_in[14] + (size_t)l * 524288;
    const float* g1_bl   = (const float*)d_in[15] + l * 2048;
    const float* g1_wr   = (const float*)d_in[16] + (size_t)l * 524288;
    const float* g1_br   = (const float*)d_in[17] + l * 2048;
    const float* g1_att  = (const float*)d_in[18] + l * 2048;
    const float* g1_bias = (const float*)d_in[19] + l * 2048;
    const float* g2_wl   = (const float*)d_in[20] + (size_t)l * 524288;
    const float* g2_bl   = (const float*)d_in[21] + l * 256;
    const float* g2_wr   = (const float*)d_in[22] + (size_t)l * 524288;
    const float* g2_br   = (const float*)d_in[23] + l * 256;
    const float* g2_att  = (const float*)d_in[24] + l * 256;
    const float* g2_bias = (const float*)d_in[25] + l * 256;
    const float* g3_wl   = (const float*)d_in[26] + (size_t)l * 524288;
    const float* g3_bl   = (const float*)d_in[27] + l * 2048;
    const float* g3_wr   = (const float*)d_in[28] + (size_t)l * 524288;
    const float* g3_br   = (const float*)d_in[29] + l * 2048;
    const float* g3_att  = (const float*)d_in[30] + l * 2048;
    const float* g3_bias = (const float*)d_in[31] + l * 2048;
    const float* g4_wl   = (const float*)d_in[32] + (size_t)l * 524288;
    const float* g4_bl   = (const float*)d_in[33] + l * 256;
    const float* g4_wr   = (const float*)d_in[34] + (size_t)l * 524288;
    const float* g4_br   = (const float*)d_in[35] + l * 256;
    const float* g4_att  = (const float*)d_in[36] + l * 256;
    const float* g4_bias = (const float*)d_in[37] + l * 256;

    float* patches = ws + OFF_ARENA;   // U (convT) / split-K partials later
    float* xs    = ws + (l == 0 ? OFF_XS0 : OFF_XS1);
    float* emb   = ws + OFF_EMB;
    float* emb2  = ws + OFF_EMB2;
    float* score = ws + OFF_LAST;
    float* xlr   = ws + OFF_XL;        // [n][4096] fused xl|xr (g1/g3); hilo split-K partials
    float* h1    = ws + OFF_H1;
    float* xlr2  = ws + OFF_XL2;       // [n][512]  fused xl|xr (g2/g4)
    float* cat   = ws + OFF_CAT;
    float* hc    = ws + OFF_HC;
    int* srcF = (int*)(ws + OFF_SRCF);
    int* srcS = (int*)(ws + OFF_SRCS);
    unsigned short* ba = (unsigned short*)(ws + OFF_BF_A);
    unsigned short* bw = (unsigned short*)(ws + OFF_BF_W);
    float* part = ws + OFF_ARENA;      // bf16 split-K partials

    // ---- conv1 patch embedding via split-precision bf16 MFMA (hi/lo) ----
    unsigned short* Ahi = (unsigned short*)(ws + OFF_ARENA);
    unsigned short* Alo = Ahi + (size_t)n * 6400;
    unsigned short* Whi = (unsigned short*)(ws + OFF_BF_A);
    unsigned short* Wlo = Whi + 1638400;
    { int tot = n * 6400;
      extract_patches_hilo_k<<<dim3((tot + 255) / 256), dim3(256), 0, s>>>(f, Ahi, Alo, nw, H, tot); }
    cast_hilo_k<<<dim3((1638400 / 4 + 255) / 256), dim3(256), 0, s>>>(conv1_w, Whi, Wlo, 1638400);
    const int S3 = (l == 0) ? 4 : 8;          // slabs per segment (K-range split)
    const int Kc1 = ((6400 / S3 + 63) / 64) * 64;
    { dim3 g(2, (n + 127) / 128, 3 * S3);
      bgemm_hilo_sk_k<<<g, dim3(256), 0, s>>>(Ahi, Alo, Whi, Wlo, xlr, n, 256, 6400, Kc1, S3); }
    { const int MN = n * 256;
      bsk_reduce_k<1, false><<<dim3((MN / 4 + 255) / 256), dim3(256), 0, s>>>(
          xlr, conv1_b, conv1_b, 256, nullptr, 0, emb, MN, 256, 3 * S3); }

    gemm32<1, true>(s, emb, fc2_w, fc2_b, emb2, n, 256, 256);

    // ---- score = emb2 @ emb2^T via hilo MFMA (emb fp32 dead; arena patches dead) ----
    unsigned short* e2hi = (unsigned short*)(ws + OFF_EMB);
    unsigned short* e2lo = e2hi + (size_t)n * 256;
    cast_hilo_k<<<dim3((n * 256 / 4 + 255) / 256), dim3(256), 0, s>>>(emb2, e2hi, e2lo, n * 256);
    { dim3 g((n + 127) / 128, (n + 127) / 128, 3);
      bgemm_hilo_sk_k<<<g, dim3(256), 0, s>>>(e2hi, e2lo, e2hi, e2lo, part, n, n, 256, 256, 1); }
    { const int MN = n * n;
      bsk_reduce_k<0, false, false><<<dim3((MN / 4 + 255) / 256), dim3(256), 0, s>>>(
          part, nullptr, nullptr, 0, nullptr, 0, score, MN, n, 3); }

    topk_feat_k<<<dim3(n), dim3(64), 0, s>>>(score, srcF, n);
    topk_spatial_k<<<dim3(n), dim3(64), 0, s>>>(srcS, n, nw);

    const int gatw1 = n * 8;   // waves for H=8 GATs
    const int gatw2 = n;       // waves for H=1 GATs

    // g1: feature graph, emb2 -> h1 [n,2048], heads=8 (fused wl|wr, N=4096; A = e2hi)
    cast_t2(s, g1_wl, g1_wr, bw, bw + 2048 * 256, 256, 2048);
    if (n >= 1024)
        bgemm<BT_NT, 0, 1, false>(s, e2hi, bw, g1_bl, g1_br, 2048, nullptr, 0, xlr, n, 4096, 256);
    else
        bgemm_sk<0, false>(s, e2hi, bw, g1_bl, g1_br, 2048, nullptr, 0, xlr, part, n, 4096, 256, 2);
    gat_fused_k<<<dim3((gatw1 + 3) / 4), dim3(256), 0, s>>>(xlr, 2048, 4096, g1_att, srcF, g1_bias, h1, n, 8, 2048, 0);

    // g2: feature graph, h1 -> cat[:, :256], heads=1 (fused, N=512, split-K 8)
    cast_bf(s, h1, ba, n * 2048);
    cast_t2(s, g2_wl, g2_wr, bw, bw + 256 * 2048, 2048, 256);
    bgemm_sk<0, false>(s, ba, bw, g2_bl, g2_br, 256, nullptr, 0, xlr2, part, n, 512, 2048, 8);
    gat_fused_k<<<dim3((gatw2 + 3) / 4), dim3(256), 0, s>>>(xlr2, 256, 512, g2_att, srcF, g2_bias, cat, n, 1, 512, 0);

    // g3: spatial graph, emb2 -> h1 [n,2048], heads=8 (reuses e2hi)
    cast_t2(s, g3_wl, g3_wr, bw, bw + 2048 * 256, 256, 2048);
    if (n >= 1024)
        bgemm<BT_NT, 0, 1, false>(s, e2hi, bw, g3_bl, g3_br, 2048, nullptr, 0, xlr, n, 4096, 256);
    else
        bgemm_sk<0, false>(s, e2hi, bw, g3_bl, g3_br, 2048, nullptr, 0, xlr, part, n, 4096, 256, 2);
    gat_fused_k<<<dim3((gatw1 + 3) / 4), dim3(256), 0, s>>>(xlr, 2048, 4096, g3_att, srcS, g3_bias, h1, n, 8, 2048, 0);

    // g4: spatial graph, h1 -> cat[:, 256:], heads=1
    cast_bf(s, h1, ba, n * 2048);
    cast_t2(s, g4_wl, g4_wr, bw, bw + 256 * 2048, 2048, 256);
    bgemm_sk<0, false>(s, ba, bw, g4_bl, g4_br, 256, nullptr, 0, xlr2, part, n, 512, 2048, 8);
    gat_fused_k<<<dim3((gatw2 + 3) / 4), dim3(256), 0, s>>>(xlr2, 256, 512, g4_att, srcS, g4_bias, cat, n, 1, 512, 256);

    // hc = relu(cat @ fc3_w^T + fc3_b) + h2   (split-K 4)
    cast_bf(s, cat, ba, n * 512);
    cast_bf(s, fc3_w, bw, 131072);
    bgemm_sk<1, true>(s, ba, bw, fc3_b, fc3_b, 256, cat + 256, 512, hc, part, n, 256, 512, 4);
    // U = hc @ convT_w
    cast_bf(s, hc, ba, n * 256);
    cast_t(s, convT_w, bw, 256, 6400);
    bgemm<BT_NT, 0, 1, false>(s, ba, bw, nullptr, nullptr, 0, nullptr, 0, patches, n, 6400, 256);
    { int tot = 256 * HW;
      scatter_convT_k<<<dim3((tot + 255) / 256), dim3(256), 0, s>>>(f, patches, convT_b, xs, nw, H, tot); }
}

extern "C" void kernel_launch(void* const* d_in, const int* in_sizes, int n_in,
                              void* d_out, int out_size, void* d_ws, size_t ws_size,
                              hipStream_t stream)
{
    float* ws  = (float*)d_ws;
    float* out = (float*)d_out;

    run_level(d_in, ws, 0, 200, stream);
    run_level(d_in, ws, 1, 100, stream);

    const float* inner_w = (const float*)d_in[2];
    const float* inner_b = (const float*)d_in[3];
    const float* layer_w = (const float*)d_in[4];
    const float* layer_b = (const float*)d_in[5];
    float* xs0    = ws + OFF_XS0;
    float* xs1    = ws + OFF_XS1;
    float* last   = ws + OFF_LAST;
    float* inner0 = ws + OFF_ARENA;
    unsigned short* bimg = (unsigned short*)(ws + OFF_XL);               // bf16 img (padded for 3x3)
    unsigned short* bw1  = (unsigned short*)(ws + OFF_BF_W);             // 1x1 weights
    unsigned short* bwc  = (unsigned short*)(ws + OFF_BF_W + 100000);    // conv3x3 reordered

    // ---- level 1: last = conv1x1(xs1); out1 = conv3x3(last) ----
    cast_t(stream, xs1, bimg, 256, 10000);
    cast_bf(stream, inner_w + 65536, bw1, 65536);
    bgemm<BT_NT, 0, 0, false>(stream, bw1, bimg, inner_b + 256, nullptr, 0, nullptr, 0,
                              last, 256, 10000, 256);
    reorder_w3_k<<<dim3((589824 + 255) / 256), dim3(256), 0, stream>>>(layer_w + 589824, bwc);
    zero_ring(stream, bimg, 100, 100);
    cast_t_pad(stream, last, nullptr, bimg, 10000, 100, 0);
    bgemm<BT_CONV2, 0, 0, false>(stream, bwc, bimg, layer_b + 256, nullptr, 0, nullptr, 0,
                                 out + 10240000, 256, 10000, 2304, 100, 100);

    // ---- level 0: inner0 = conv1x1(xs0); pad-cast fuses +nearest(last); out0 = conv3x3 ----
    cast_t(stream, xs0, bimg, 256, 40000);
    cast_bf(stream, inner_w, bw1, 65536);
    bgemm<BT_NT, 0, 0, false>(stream, bw1, bimg, inner_b, nullptr, 0, nullptr, 0,
                              inner0, 256, 40000, 256);
    reorder_w3_k<<<dim3((589824 + 255) / 256), dim3(256), 0, stream>>>(layer_w, bwc);
    zero_ring(stream, bimg, 200, 200);
    cast_t_pad(stream, inner0, last, bimg, 40000, 200, 100);
    bgemm<BT_CONV2, 0, 0, false>(stream, bwc, bimg, layer_b, nullptr, 0, nullptr, 0,
                                 out, 256, 40000, 2304, 200, 200);
}

// Round 7
// 1100.867 us; speedup vs baseline: 1.0142x; 1.0142x over previous
//
#include <hip/hip_runtime.h>
#include <cstdint>
#include <cstddef>
#include <math.h>

#define KNN 7

using short8  = __attribute__((ext_vector_type(8))) short;
using floatx4 = __attribute__((ext_vector_type(4))) float;

// ---------------- workspace layout (in floats) ----------------
static const size_t OFF_ARENA = 0;          // 10,240,000  patch hi/lo bf16 / split-K partials
static const size_t OFF_XS0   = 10240000;   // 10,240,000
static const size_t OFF_XS1   = 20480000;   //  2,560,000
static const size_t OFF_LAST  = 23040000;   //  2,560,000  score (GNN) / last (FPN)
static const size_t OFF_EMB   = 25600000;   //    409,600  e2hi|e2lo bf16
static const size_t OFF_EMB2  = 26009600;   //    409,600  embHi|embLo bf16
static const size_t OFF_XL    = 26419200;   //  6,553,600 xlr / hilo-splitK part / FPN bf16 img
static const size_t OFF_H1    = 32972800;   //  3,276,800  h1 bf16
static const size_t OFF_XL2   = 36249600;   //    819,200 (xlr2)
static const size_t OFF_CAT   = 37068800;   //    819,200  cat fp32
static const size_t OFF_HC    = 37888000;   //    409,600  hc bf16
static const size_t OFF_SRCF  = 38400000;   //     11,200 ints
static const size_t OFF_SRCS  = 38411200;   //     11,200 ints
static const size_t OFF_BF_A  = 38422400;   //  1,700,000 floats (conv1 W hi+lo / cat bf16)
static const size_t OFF_BF_W  = 40122400;   //    850,000 floats (W casts)
// total ~164 MB

static __device__ __forceinline__ unsigned short f2bf(float f) {
    union { float f; unsigned u; } v; v.f = f;
    unsigned u = v.u;
    unsigned r = u + 0x7fffu + ((u >> 16) & 1u);   // RNE
    return (unsigned short)(r >> 16);
}

static __device__ __forceinline__ float bf2f(unsigned short h) {
    union { unsigned u; float f; } v; v.u = ((unsigned)h) << 16; return v.f;
}

// async global->LDS, 16B per lane. LDS dest is wave-uniform base + lane*16.
static __device__ __forceinline__ void glds16(const void* g, void* l) {
    __builtin_amdgcn_global_load_lds((const __attribute__((address_space(1))) void*)g,
                                     (__attribute__((address_space(3))) void*)l, 16, 0, 0);
}

// ============================ bf16 MFMA GEMM ======
// Hybrid pipelines (both counted-vmcnt, both-sides swizzle, glds-staged):
//  - BT_NT:    BK=64, 2 LDS buffers (64 KB), vmcnt(8).
//  - BT_CONV2: BK=32, 3 LDS buffers (48 KB -> 3 blocks/CU), vmcnt(4),
//              stage-before-compute (2-phase slack). Proven structure.
// EPI==1 (NT only): fused ConvT scatter epilogue:
//   o=n/25,a,b from n; mh=m/nw, ml=m%nw; ix=o*H*H+(ml*5+a)*H+mh*5+b;
//   C[ix] = fEP[ix] + relu(acc + bEP[o]).   (C = xs base)
enum { BT_NT = 0, BT_CONV2 = 2 };

template<int BT, int ACT, int BAX, bool ADDMAT, int EPI>
__global__ __launch_bounds__(256)
void bgemm_k(const unsigned short* __restrict__ A, const unsigned short* __restrict__ B,
             const float* __restrict__ bias, const float* __restrict__ bias2, int nsplit,
             const float* __restrict__ Dmat, int Dld,
             float* __restrict__ C, int M, int N, int K, int imH, int imW,
             const float* __restrict__ fEP, const float* __restrict__ bEP, int nwEP)
{
    constexpr int LDS_SH = (BT == BT_CONV2) ? 3 * 4096 : 2 * 8192;
    __shared__ unsigned short As[LDS_SH];
    __shared__ unsigned short Bs[LDS_SH];
    const int tid  = threadIdx.x;
    const int lane = tid & 63;
    const int wid  = tid >> 6;
    const int quad = lane >> 4;
    const int l15  = lane & 15;
    const int wy = wid >> 1, wx = wid & 1;

    // block-id swizzle (gridDim.y==2 shapes: conv + 1x1): XCD-chunked bijective.
    int bxx = blockIdx.x, byy = blockIdx.y;
    if (gridDim.y == 2) {
        const int nbx = gridDim.x;
        const int nwg = nbx * 2;
        const int hw  = byy * nbx + bxx;
        const int q = nwg >> 3, r = nwg & 7;
        const int x8 = hw & 7, d = hw >> 3;
        const int lg = (x8 < r) ? x8 * (q + 1) + d : r * (q + 1) + (x8 - r) * q + d;
        byy = lg & 1; bxx = lg >> 1;
    }
    const int bm0 = byy * 128;
    const int bn0 = bxx * 128;

    floatx4 zero = {0.f, 0.f, 0.f, 0.f};
    floatx4 acc[4][4];
    #pragma unroll
    for (int i = 0; i < 4; i++)
        #pragma unroll
        for (int j = 0; j < 4; j++) acc[i][j] = zero;

    if constexpr (BT == BT_CONV2) {
        // ---------- BK=32, 3-buffer pipeline ----------
        const int l4 = lane >> 2;
        const int swc = (((lane & 3) ^ ((lane >> 3) & 3)) << 3);   // shorts
        const int r0 = wid * 32 + l4;
        const int r1 = r0 + 16;
        int am0 = bm0 + r0; if (am0 > M - 1) am0 = M - 1;
        int am1 = bm0 + r1; if (am1 > M - 1) am1 = M - 1;
        const unsigned short* aP0 = A + (size_t)am0 * K + swc;
        const unsigned short* aP1 = A + (size_t)am1 * K + swc;
        const int W2 = imW + 2;
        int pp0 = bn0 + r0; if (pp0 > N - 1) pp0 = N - 1;
        int pp1 = bn0 + r1; if (pp1 > N - 1) pp1 = N - 1;
        const int py0 = pp0 / imW, px0 = pp0 - py0 * imW;
        const int py1 = pp1 / imW, px1 = pp1 - py1 * imW;
        const unsigned short* bP0 = B + ((size_t)(py0 + 1) * W2 + px0 + 1) * 256 + swc;
        const unsigned short* bP1 = B + ((size_t)(py1 + 1) * W2 + px1 + 1) * 256 + swc;

        auto stage = [&](int buf, int t) {
            const int k0 = t << 5;
            glds16(aP0 + k0, &As[buf * 4096 + wid * 1024]);
            glds16(aP1 + k0, &As[buf * 4096 + wid * 1024 + 512]);
            const int jj = k0 >> 8;              // tap 0..8 (uniform scalar)
            const int j3 = jj / 3;
            const ptrdiff_t toff = (ptrdiff_t)((j3 - 1) * W2 + (jj - j3 * 3 - 1)) * 256
                                 + (k0 & 255);
            glds16(bP0 + toff, &Bs[buf * 4096 + wid * 1024]);
            glds16(bP1 + toff, &Bs[buf * 4096 + wid * 1024 + 512]);
        };
        const int rsw = ((quad ^ ((l15 >> 1) & 3)) << 3);   // shorts
        auto compute = [&](int buf) {
            short8 af[4], bfr[4];
            #pragma unroll
            for (int i = 0; i < 4; i++)
                af[i] = *(const short8*)&As[buf * 4096 + (wy * 64 + i * 16 + l15) * 32 + rsw];
            #pragma unroll
            for (int j = 0; j < 4; j++)
                bfr[j] = *(const short8*)&Bs[buf * 4096 + (wx * 64 + j * 16 + l15) * 32 + rsw];
            #pragma unroll
            for (int i = 0; i < 4; i++)
                #pragma unroll
                for (int j = 0; j < 4; j++)
                    acc[i][j] = __builtin_amdgcn_mfma_f32_16x16x32_bf16(af[i], bfr[j], acc[i][j], 0, 0, 0);
        };

        const int T = K >> 5;
        stage(0, 0);
        if (T > 1) stage(1, 1);
        int cb = 0, sb = 2;
        for (int t = 0; t < T; t++) {
            if (t < T - 1) asm volatile("s_waitcnt vmcnt(4) lgkmcnt(0)" ::: "memory");
            else           asm volatile("s_waitcnt vmcnt(0) lgkmcnt(0)" ::: "memory");
            __builtin_amdgcn_s_barrier();
            __builtin_amdgcn_sched_barrier(0);
            if (t + 2 < T) stage(sb, t + 2);
            compute(cb);
            cb = (cb == 2) ? 0 : cb + 1;
            sb = (sb == 2) ? 0 : sb + 1;
        }
    } else {
        // ---------- BK=64, 2-buffer pipeline ----------
        const int l8 = lane >> 3;
        const int swq = (((lane & 7) ^ (l8 & 7)) << 3);   // swizzled source chunk
        const unsigned short* aP[4];
        const unsigned short* bP[4];
        #pragma unroll
        for (int g = 0; g < 4; g++) {
            int ra = bm0 + wid * 32 + g * 8 + l8;
            if (ra > M - 1) ra = M - 1;
            aP[g] = A + (size_t)ra * K + swq;
            int rb = bn0 + wid * 32 + g * 8 + l8;
            if (rb > N - 1) rb = N - 1;
            bP[g] = B + (size_t)rb * K + swq;
        }

        auto stage = [&](int buf, int t) {
            const int k0 = t << 6;
            #pragma unroll
            for (int g = 0; g < 4; g++)
                glds16(aP[g] + k0, &As[buf * 8192 + wid * 2048 + g * 512]);
            #pragma unroll
            for (int g = 0; g < 4; g++)
                glds16(bP[g] + k0, &Bs[buf * 8192 + wid * 2048 + g * 512]);
        };
        auto compute = [&](int buf) {
            #pragma unroll
            for (int ks = 0; ks < 2; ks++) {
                short8 af[4], bfr[4];
                #pragma unroll
                for (int i = 0; i < 4; i++)
                    af[i] = *(const short8*)&As[buf * 8192 + (wy * 64 + i * 16 + l15) * 64
                                                + (((ks * 4 + quad) ^ (l15 & 7)) << 3)];
                #pragma unroll
                for (int j = 0; j < 4; j++)
                    bfr[j] = *(const short8*)&Bs[buf * 8192 + (wx * 64 + j * 16 + l15) * 64
                                                 + (((ks * 4 + quad) ^ (l15 & 7)) << 3)];
                #pragma unroll
                for (int i = 0; i < 4; i++)
                    #pragma unroll
                    for (int j = 0; j < 4; j++)
                        acc[i][j] = __builtin_amdgcn_mfma_f32_16x16x32_bf16(af[i], bfr[j], acc[i][j], 0, 0, 0);
            }
        };

        const int T2 = K >> 6;
        stage(0, 0);
        if (T2 > 1) stage(1, 1);
        for (int t = 0; t < T2; t++) {
            if (t + 1 < T2) asm volatile("s_waitcnt vmcnt(8) lgkmcnt(0)" ::: "memory");
            else            asm volatile("s_waitcnt vmcnt(0) lgkmcnt(0)" ::: "memory");
            __builtin_amdgcn_s_barrier();
            __builtin_amdgcn_sched_barrier(0);
            compute(t & 1);
            __builtin_amdgcn_s_barrier();
            __builtin_amdgcn_sched_barrier(0);
            if (t + 2 < T2) stage(t & 1, t + 2);
        }
    }

    #pragma unroll
    for (int i = 0; i < 4; i++) {
        #pragma unroll
        for (int r = 0; r < 4; r++) {
            const int m = bm0 + wy * 64 + i * 16 + quad * 4 + r;
            if (m >= M) continue;
            #pragma unroll
            for (int j = 0; j < 4; j++) {
                const int n = bn0 + wx * 64 + j * 16 + l15;
                if (n >= N) continue;
                float v = acc[i][j][r];
                if (EPI == 1) {
                    const int o = n / 25;
                    const int rm = n - o * 25;
                    const int a2 = rm / 5, b2 = rm - (rm / 5) * 5;
                    const int mh = m / nwEP, ml = m - (m / nwEP) * nwEP;
                    const size_t ix = (size_t)o * imH * imH + (size_t)(ml * 5 + a2) * imH
                                    + mh * 5 + b2;
                    v = fmaxf(v + bEP[o], 0.f);
                    C[ix] = fEP[ix] + v;
                } else {
                    if (bias != nullptr)
                        v += (BAX == 0) ? bias[m] : (n < nsplit ? bias[n] : bias2[n - nsplit]);
                    if (ACT == 1) v = fmaxf(v, 0.f);
                    if (ADDMAT) v += Dmat[(size_t)m * Dld + n];
                    C[(size_t)m * N + n] = v;
                }
            }
        }
    }
}

template<int BT, int ACT, int BAX, bool ADDMAT>
static inline void bgemm(hipStream_t s, const unsigned short* A, const unsigned short* B,
                         const float* bias, const float* bias2, int nsplit,
                         const float* D, int Dld, float* C,
                         int M, int N, int K, int imH = 0, int imW = 0)
{
    dim3 g((N + 127) / 128, (M + 127) / 128);
    bgemm_k<BT, ACT, BAX, ADDMAT, 0><<<g, dim3(256), 0, s>>>(A, B, bias, bias2, nsplit,
                                                             D, Dld, C, M, N, K, imH, imW,
                                                             nullptr, nullptr, 0);
}

static inline void bgemm_convT(hipStream_t s, const unsigned short* A, const unsigned short* B,
                               const float* f, const float* cb, float* xs,
                               int M, int nw, int H)
{
    dim3 g((6400 + 127) / 128, (M + 127) / 128);
    bgemm_k<BT_NT, 0, 0, false, 1><<<g, dim3(256), 0, s>>>(A, B, nullptr, nullptr, 0,
                                                           nullptr, 0, xs, M, 6400, 256, H, 0,
                                                           f, cb, nw);
}

// ---- bf16 split-K (NT only): partials fp32; BK=64 pipeline ----
__global__ __launch_bounds__(256)
void bgemm_sk_k(const unsigned short* __restrict__ A, const unsigned short* __restrict__ B,
                float* __restrict__ part, int M, int N, int K, int Kc)
{
    __shared__ unsigned short As[2][8192];
    __shared__ unsigned short Bs[2][8192];
    const int tid  = threadIdx.x;
    const int lane = tid & 63;
    const int wid  = tid >> 6;
    const int quad = lane >> 4;
    const int l15  = lane & 15;
    const int l8   = lane >> 3;
    const int wy = wid >> 1, wx = wid & 1;
    const int bm0 = blockIdx.y * 128;
    const int bn0 = blockIdx.x * 128;
    const int kbeg = blockIdx.z * Kc;
    const int kend = (kbeg + Kc < K) ? kbeg + Kc : K;

    floatx4 zero = {0.f, 0.f, 0.f, 0.f};
    floatx4 acc[4][4];
    #pragma unroll
    for (int i = 0; i < 4; i++)
        #pragma unroll
        for (int j = 0; j < 4; j++) acc[i][j] = zero;

    const int swq = (((lane & 7) ^ (l8 & 7)) << 3);
    const unsigned short* aP[4];
    const unsigned short* bP[4];
    #pragma unroll
    for (int g = 0; g < 4; g++) {
        int ra = bm0 + wid * 32 + g * 8 + l8;
        if (ra > M - 1) ra = M - 1;
        aP[g] = A + (size_t)ra * K + kbeg + swq;
        int rb = bn0 + wid * 32 + g * 8 + l8;
        if (rb > N - 1) rb = N - 1;
        bP[g] = B + (size_t)rb * K + kbeg + swq;
    }

    auto stage = [&](int buf, int t) {
        const int k0 = t << 6;
        #pragma unroll
        for (int g = 0; g < 4; g++)
            glds16(aP[g] + k0, &As[buf][wid * 2048 + g * 512]);
        #pragma unroll
        for (int g = 0; g < 4; g++)
            glds16(bP[g] + k0, &Bs[buf][wid * 2048 + g * 512]);
    };
    auto compute = [&](int buf) {
        #pragma unroll
        for (int ks = 0; ks < 2; ks++) {
            short8 af[4], bfr[4];
            #pragma unroll
            for (int i = 0; i < 4; i++)
                af[i] = *(const short8*)&As[buf][(wy * 64 + i * 16 + l15) * 64
                                                 + (((ks * 4 + quad) ^ (l15 & 7)) << 3)];
            #pragma unroll
            for (int j = 0; j < 4; j++)
                bfr[j] = *(const short8*)&Bs[buf][(wx * 64 + j * 16 + l15) * 64
                                                  + (((ks * 4 + quad) ^ (l15 & 7)) << 3)];
            #pragma unroll
            for (int i = 0; i < 4; i++)
                #pragma unroll
                for (int j = 0; j < 4; j++)
                    acc[i][j] = __builtin_amdgcn_mfma_f32_16x16x32_bf16(af[i], bfr[j], acc[i][j], 0, 0, 0);
        }
    };

    const int T2 = (kend - kbeg) >> 6;
    stage(0, 0);
    if (T2 > 1) stage(1, 1);
    for (int t = 0; t < T2; t++) {
        if (t + 1 < T2) asm volatile("s_waitcnt vmcnt(8) lgkmcnt(0)" ::: "memory");
        else            asm volatile("s_waitcnt vmcnt(0) lgkmcnt(0)" ::: "memory");
        __builtin_amdgcn_s_barrier();
        __builtin_amdgcn_sched_barrier(0);
        compute(t & 1);
        __builtin_amdgcn_s_barrier();
        __builtin_amdgcn_sched_barrier(0);
        if (t + 2 < T2) stage(t & 1, t + 2);
    }

    float* P = part + (size_t)blockIdx.z * M * N;
    #pragma unroll
    for (int i = 0; i < 4; i++) {
        #pragma unroll
        for (int r = 0; r < 4; r++) {
            const int m = bm0 + wy * 64 + i * 16 + quad * 4 + r;
            if (m >= M) continue;
            #pragma unroll
            for (int j = 0; j < 4; j++) {
                const int n = bn0 + wx * 64 + j * 16 + l15;
                if (n >= N) continue;
                P[(size_t)m * N + n] = acc[i][j][r];
            }
        }
    }
}

// ---- split-precision (hi/lo bf16) fp32-emulating split-K GEMM ----
// C = A*B as Ahi*Bhi + Alo*Bhi + Ahi*Blo (missing lo*lo ~ 2^-18).
// blockIdx.z = seg * S3 + slab. Slab lengths must be %64 == 0.
__global__ __launch_bounds__(256)
void bgemm_hilo_sk_k(const unsigned short* __restrict__ Ahi, const unsigned short* __restrict__ Alo,
                     const unsigned short* __restrict__ Bhi, const unsigned short* __restrict__ Blo,
                     float* __restrict__ part, int M, int N, int K, int Kc, int S3)
{
    __shared__ unsigned short As[2][8192];
    __shared__ unsigned short Bs[2][8192];
    const int tid  = threadIdx.x;
    const int lane = tid & 63;
    const int wid  = tid >> 6;
    const int quad = lane >> 4;
    const int l15  = lane & 15;
    const int l8   = lane >> 3;
    const int wy = wid >> 1, wx = wid & 1;
    const int bm0 = blockIdx.y * 128;
    const int bn0 = blockIdx.x * 128;

    const int seg  = blockIdx.z / S3;
    const int slab = blockIdx.z - seg * S3;
    const unsigned short* A = (seg == 1) ? Alo : Ahi;
    const unsigned short* B = (seg == 2) ? Blo : Bhi;
    const int kbeg = slab * Kc;
    const int kend = (kbeg + Kc < K) ? kbeg + Kc : K;

    floatx4 zero = {0.f, 0.f, 0.f, 0.f};
    floatx4 acc[4][4];
    #pragma unroll
    for (int i = 0; i < 4; i++)
        #pragma unroll
        for (int j = 0; j < 4; j++) acc[i][j] = zero;

    const int swq = (((lane & 7) ^ (l8 & 7)) << 3);
    const unsigned short* aP[4];
    const unsigned short* bP[4];
    #pragma unroll
    for (int g = 0; g < 4; g++) {
        int ra = bm0 + wid * 32 + g * 8 + l8;
        if (ra > M - 1) ra = M - 1;
        aP[g] = A + (size_t)ra * K + kbeg + swq;
        int rb = bn0 + wid * 32 + g * 8 + l8;
        if (rb > N - 1) rb = N - 1;
        bP[g] = B + (size_t)rb * K + kbeg + swq;
    }

    auto stage = [&](int buf, int t) {
        const int k0 = t << 6;
        #pragma unroll
        for (int g = 0; g < 4; g++)
            glds16(aP[g] + k0, &As[buf][wid * 2048 + g * 512]);
        #pragma unroll
        for (int g = 0; g < 4; g++)
            glds16(bP[g] + k0, &Bs[buf][wid * 2048 + g * 512]);
    };
    auto compute = [&](int buf) {
        #pragma unroll
        for (int ks = 0; ks < 2; ks++) {
            short8 af[4], bfr[4];
            #pragma unroll
            for (int i = 0; i < 4; i++)
                af[i] = *(const short8*)&As[buf][(wy * 64 + i * 16 + l15) * 64
                                                 + (((ks * 4 + quad) ^ (l15 & 7)) << 3)];
            #pragma unroll
            for (int j = 0; j < 4; j++)
                bfr[j] = *(const short8*)&Bs[buf][(wx * 64 + j * 16 + l15) * 64
                                                  + (((ks * 4 + quad) ^ (l15 & 7)) << 3)];
            #pragma unroll
            for (int i = 0; i < 4; i++)
                #pragma unroll
                for (int j = 0; j < 4; j++)
                    acc[i][j] = __builtin_amdgcn_mfma_f32_16x16x32_bf16(af[i], bfr[j], acc[i][j], 0, 0, 0);
        }
    };

    const int T2 = (kend - kbeg) >> 6;
    stage(0, 0);
    if (T2 > 1) stage(1, 1);
    for (int t = 0; t < T2; t++) {
        if (t + 1 < T2) asm volatile("s_waitcnt vmcnt(8) lgkmcnt(0)" ::: "memory");
        else            asm volatile("s_waitcnt vmcnt(0) lgkmcnt(0)" ::: "memory");
        __builtin_amdgcn_s_barrier();
        __builtin_amdgcn_sched_barrier(0);
        compute(t & 1);
        __builtin_amdgcn_s_barrier();
        __builtin_amdgcn_sched_barrier(0);
        if (t + 2 < T2) stage(t & 1, t + 2);
    }

    float* P = part + (size_t)blockIdx.z * M * N;
    #pragma unroll
    for (int i = 0; i < 4; i++) {
        #pragma unroll
        for (int r = 0; r < 4; r++) {
            const int m = bm0 + wy * 64 + i * 16 + quad * 4 + r;
            if (m >= M) continue;
            #pragma unroll
            for (int j = 0; j < 4; j++) {
                const int n = bn0 + wx * 64 + j * 16 + l15;
                if (n >= N) continue;
                P[(size_t)m * N + n] = acc[i][j][r];
            }
        }
    }
}

// reduce S slabs + optional dual-bias(axis n) + relu + addmat.
// OUT: 0 = fp32 C; 1 = bf16 Chi; 2 = hi/lo bf16 pair (Chi, Clo).
template<int ACT, bool ADDMAT, bool BIAS, int OUT>
__global__ void bsk_reduce_k(const float* __restrict__ part,
                             const float* __restrict__ bias, const float* __restrict__ bias2,
                             int nsplit, const float* __restrict__ Dmat, int Dld,
                             float* __restrict__ C, unsigned short* __restrict__ Chi,
                             unsigned short* __restrict__ Clo,
                             int MN, int N, int S)
{
    const int i4 = (blockIdx.x * 256 + threadIdx.x) * 4;
    if (i4 >= MN) return;
    float4 a = *(const float4*)(part + i4);
    for (int s = 1; s < S; s++) {
        const float4 b = *(const float4*)(part + (size_t)s * MN + i4);
        a.x += b.x; a.y += b.y; a.z += b.z; a.w += b.w;
    }
    const int n = i4 % N;
    if (BIAS) {
        const float* bb = (n < nsplit) ? (bias + n) : (bias2 + n - nsplit);
        a.x += bb[0]; a.y += bb[1]; a.z += bb[2]; a.w += bb[3];
    }
    if (ACT == 1) {
        a.x = fmaxf(a.x, 0.f); a.y = fmaxf(a.y, 0.f);
        a.z = fmaxf(a.z, 0.f); a.w = fmaxf(a.w, 0.f);
    }
    if (ADDMAT) {
        const int m = i4 / N;
        const float4 d = *(const float4*)(Dmat + (size_t)m * Dld + n);
        a.x += d.x; a.y += d.y; a.z += d.z; a.w += d.w;
    }
    if (OUT == 0) {
        *(float4*)(C + i4) = a;
    } else if (OUT == 1) {
        ushort4 h;
        h.x = f2bf(a.x); h.y = f2bf(a.y); h.z = f2bf(a.z); h.w = f2bf(a.w);
        *(ushort4*)(Chi + i4) = h;
    } else {
        ushort4 h, l;
        h.x = f2bf(a.x); l.x = f2bf(a.x - bf2f(h.x));
        h.y = f2bf(a.y); l.y = f2bf(a.y - bf2f(h.y));
        h.z = f2bf(a.z); l.z = f2bf(a.z - bf2f(h.z));
        h.w = f2bf(a.w); l.w = f2bf(a.w - bf2f(h.w));
        *(ushort4*)(Chi + i4) = h;
        *(ushort4*)(Clo + i4) = l;
    }
}

template<int ACT, bool ADDMAT>
static inline void bgemm_sk(hipStream_t s, const unsigned short* A, const unsigned short* B,
                            const float* bias, const float* bias2, int nsplit,
                            const float* D, int Dld, float* C, float* part,
                            int M, int N, int K, int S)
{
    const int Kc = ((K / S + 63) / 64) * 64;
    dim3 g((N + 127) / 128, (M + 127) / 128, S);
    bgemm_sk_k<<<g, dim3(256), 0, s>>>(A, B, part, M, N, K, Kc);
    const int MN = M * N;
    bsk_reduce_k<ACT, ADDMAT, true, 0><<<dim3((MN / 4 + 255) / 256), dim3(256), 0, s>>>(
        part, bias, bias2, nsplit, D, Dld, C, nullptr, nullptr, MN, N, S);
}

// ============================ cast / reorder kernels ============================
__global__ void cast_bf16_k(const float* __restrict__ in, unsigned short* __restrict__ out, int total)
{
    const int i4 = (blockIdx.x * 256 + threadIdx.x) * 4;
    if (i4 + 4 <= total) {
        const float4 v = *(const float4*)(in + i4);
        ushort4 o;
        o.x = f2bf(v.x); o.y = f2bf(v.y); o.z = f2bf(v.z); o.w = f2bf(v.w);
        *(ushort4*)(out + i4) = o;
    } else {
        for (int i = i4; i < total; i++) out[i] = f2bf(in[i]);
    }
}

static inline void cast_bf(hipStream_t s, const float* in, unsigned short* out, int total)
{
    cast_bf16_k<<<dim3((total / 4 + 255) / 256), dim3(256), 0, s>>>(in, out, total);
}

// elementwise hi/lo split cast
__global__ void cast_hilo_k(const float* __restrict__ in, unsigned short* __restrict__ hi,
                            unsigned short* __restrict__ lo, int total)
{
    const int i4 = (blockIdx.x * 256 + threadIdx.x) * 4;
    if (i4 + 4 <= total) {
        const float4 v = *(const float4*)(in + i4);
        ushort4 h, l;
        h.x = f2bf(v.x); l.x = f2bf(v.x - bf2f(h.x));
        h.y = f2bf(v.y); l.y = f2bf(v.y - bf2f(h.y));
        h.z = f2bf(v.z); l.z = f2bf(v.z - bf2f(h.z));
        h.w = f2bf(v.w); l.w = f2bf(v.w - bf2f(h.w));
        *(ushort4*)(hi + i4) = h;
        *(ushort4*)(lo + i4) = l;
    } else {
        for (int i = i4; i < total; i++) {
            unsigned short h = f2bf(in[i]);
            hi[i] = h; lo[i] = f2bf(in[i] - bf2f(h));
        }
    }
}

__device__ __forceinline__ void cast_t_body(const float* __restrict__ in,
                                            unsigned short* __restrict__ out, int K, int N)
{
    __shared__ float tile[64][65];
    const int n0 = blockIdx.x * 64;
    const int k0 = blockIdx.y * 64;
    const int t = threadIdx.x;
    const int r = t >> 2;
    const int c4 = (t & 3) << 4;
    {
        const int k = k0 + r;
        if (k < K && n0 + c4 + 16 <= N) {
            const float4* p = (const float4*)(in + (size_t)k * N + n0 + c4);
            *(float4*)&tile[r][c4]      = p[0];
            *(float4*)&tile[r][c4 + 4]  = p[1];
            *(float4*)&tile[r][c4 + 8]  = p[2];
            *(float4*)&tile[r][c4 + 12] = p[3];
        } else {
            for (int i = 0; i < 16; i++)
                tile[r][c4 + i] = (k < K && n0 + c4 + i < N) ? in[(size_t)k * N + n0 + c4 + i] : 0.f;
        }
    }
    __syncthreads();
    const int n = n0 + r;
    if (n >= N) return;
    unsigned short tmp[16];
    #pragma unroll
    for (int i = 0; i < 16; i++) tmp[i] = f2bf(tile[c4 + i][r]);
    if (k0 + 64 <= K) {
        *(uint4*)(out + (size_t)n * K + k0 + c4)     = *(uint4*)&tmp[0];
        *(uint4*)(out + (size_t)n * K + k0 + c4 + 8) = *(uint4*)&tmp[8];
    } else {
        for (int i = 0; i < 16; i++)
            if (k0 + c4 + i < K) out[(size_t)n * K + k0 + c4 + i] = tmp[i];
    }
}

__global__ void cast_t_k(const float* __restrict__ in, unsigned short* __restrict__ out, int K, int N)
{
    cast_t_body(in, out, K, N);
}

__global__ void cast_t2_k(const float* __restrict__ in0, const float* __restrict__ in1,
                          unsigned short* __restrict__ out0, unsigned short* __restrict__ out1,
                          int K, int N)
{
    if (blockIdx.z == 0) cast_t_body(in0, out0, K, N);
    else                 cast_t_body(in1, out1, K, N);
}

static inline void cast_t(hipStream_t s, const float* in, unsigned short* out, int K, int N)
{
    cast_t_k<<<dim3((N + 63) / 64, (K + 63) / 64), dim3(256), 0, s>>>(in, out, K, N);
}

static inline void cast_t2(hipStream_t s, const float* in0, const float* in1,
                           unsigned short* out0, unsigned short* out1, int K, int N)
{
    cast_t2_k<<<dim3((N + 63) / 64, (K + 63) / 64, 2), dim3(256), 0, s>>>(in0, in1, out0, out1, K, N);
}

// transpose-cast [256][N] fp32 -> ZERO-PADDED bf16 image [(imH+2)(imW+2)][256]
// grid.y==4 plane zeroes the border ring; planes 0..3 are K-chunks.
// optional fused nearest-2x upsample-add: + up[c][py>>1][px>>1]
__global__ void cast_t_pad_k(const float* __restrict__ in, const float* __restrict__ up,
                             unsigned short* __restrict__ out, int N, int imW, int upW)
{
    if (blockIdx.y == 4) {           // border ring zeroing
        const int imH = N / imW;
        const int W2 = imW + 2;
        const int nb = 2 * W2 + 2 * imH;
        const int idx = blockIdx.x * 256 + threadIdx.x;
        if (idx >= nb * 32) return;
        const int p = idx >> 5;
        const int c8 = (idx & 31) << 3;
        int row;
        if (p < W2)            row = p;
        else if (p < 2 * W2)   row = (imH + 1) * W2 + (p - W2);
        else { const int q = p - 2 * W2; const int y = q >> 1;
               row = (y + 1) * W2 + ((q & 1) ? (imW + 1) : 0); }
        *(uint4*)(out + (size_t)row * 256 + c8) = (uint4){0, 0, 0, 0};
        return;
    }
    __shared__ float tile[64][65];
    const int n0 = blockIdx.x * 64;
    const int k0 = blockIdx.y * 64;   // 0..3 * 64, K = 256
    const int t = threadIdx.x;
    const int r = t >> 2;
    const int c4 = (t & 3) << 4;
    {
        const int k = k0 + r;
        if (n0 + c4 + 16 <= N) {
            const float4* p = (const float4*)(in + (size_t)k * N + n0 + c4);
            *(float4*)&tile[r][c4]      = p[0];
            *(float4*)&tile[r][c4 + 4]  = p[1];
            *(float4*)&tile[r][c4 + 8]  = p[2];
            *(float4*)&tile[r][c4 + 12] = p[3];
        } else {
            for (int i = 0; i < 16; i++)
                tile[r][c4 + i] = (n0 + c4 + i < N) ? in[(size_t)k * N + n0 + c4 + i] : 0.f;
        }
    }
    __syncthreads();
    const int n = n0 + r;
    if (n >= N) return;
    const int py = n / imW, px = n - py * imW;
    unsigned short tmp[16];
    if (up != nullptr) {
        const float* u = up + (size_t)(py >> 1) * upW + (px >> 1);
        #pragma unroll
        for (int i = 0; i < 16; i++)
            tmp[i] = f2bf(tile[c4 + i][r] + u[(size_t)(k0 + c4 + i) * upW * upW]);
    } else {
        #pragma unroll
        for (int i = 0; i < 16; i++) tmp[i] = f2bf(tile[c4 + i][r]);
    }
    unsigned short* o = out + ((size_t)(py + 1) * (imW + 2) + px + 1) * 256 + k0 + c4;
    *(uint4*)(o)     = *(uint4*)&tmp[0];
    *(uint4*)(o + 8) = *(uint4*)&tmp[8];
}

static inline void cast_t_pad(hipStream_t s, const float* in, const float* up,
                              unsigned short* out, int N, int imW, int upW)
{
    cast_t_pad_k<<<dim3((N + 63) / 64, 5), dim3(256), 0, s>>>(in, up, out, N, imW, upW);
}

__global__ void reorder_w3_k(const float* __restrict__ in, unsigned short* __restrict__ out)
{
    const int idx = blockIdx.x * 256 + threadIdx.x;
    if (idx >= 589824) return;
    const int o = idx / 2304;
    const int r = idx - o * 2304;
    const int j = r >> 8;
    const int c = r & 255;
    out[idx] = f2bf(in[(size_t)o * 2304 + c * 9 + j]);
}

// ============================ small kernels ============================
// extract patches directly into hi/lo bf16 A-matrices [n][6400]
__global__ void extract_patches_hilo_k(const float* __restrict__ f,
                                       unsigned short* __restrict__ hi,
                                       unsigned short* __restrict__ lo,
                                       int nw, int H, int total)
{
    int idx = blockIdx.x * 256 + threadIdx.x;
    if (idx >= total) return;
    int q = idx % 6400;
    int p = idx / 6400;
    int c = q / 25;
    int rem = q - c * 25;
    int a = rem / 5, b = rem - (rem / 5) * 5;
    int ih = p / nw, iw = p - (p / nw) * nw;
    const float v = f[(size_t)c * H * H + (size_t)(ih * 5 + a) * H + (iw * 5 + b)];
    const unsigned short h = f2bf(v);
    hi[idx] = h;
    lo[idx] = f2bf(v - bf2f(h));
}

__global__ void topk_feat_k(const float* __restrict__ score, int* __restrict__ srcCols, int n)
{
    const int r = blockIdx.x;
    const int lane = threadIdx.x;
    const float* row = score + (size_t)r * n;
    int   sel[KNN];
    float selv[KNN];
    #pragma unroll
    for (int t = 0; t < KNN; t++) {
        float best = -__builtin_huge_valf();
        int   bidx = 0x7fffffff;
        for (int c = lane; c < n; c += 64) {
            bool taken = false;
            #pragma unroll
            for (int u = 0; u < KNN; u++)
                if (u < t && sel[u] == c) taken = true;
            if (taken) continue;
            float v = row[c];
            if (v > best || (v == best && c < bidx)) { best = v; bidx = c; }
        }
        #pragma unroll
        for (int off = 32; off > 0; off >>= 1) {
            float ov = __shfl_down(best, off);
            int   oi = __shfl_down(bidx, off);
            if (ov > best || (ov == best && oi < bidx)) { best = ov; bidx = oi; }
        }
        best = __shfl(best, 0);
        bidx = __shfl(bidx, 0);
        sel[t] = bidx; selv[t] = best;
    }
    if (lane < KNN) {
        int c = -1; float v = 0.f;
        #pragma unroll
        for (int t = 0; t < KNN; t++)
            if (lane == t) { c = sel[t]; v = selv[t]; }
        srcCols[r * KNN + lane] = (c > r && v != 0.0f) ? c : -1;
    }
}

__global__ void topk_spatial_k(int* __restrict__ srcCols, int n, int nw)
{
    const int r = blockIdx.x;
    const int lane = threadIdx.x;
    const int ri = r / nw, rj = r - (r / nw) * nw;
    int sel[KNN];
    #pragma unroll
    for (int t = 0; t < KNN; t++) {
        int bkey = 0x7fffffff;
        for (int c = lane; c < n; c += 64) {
            bool taken = false;
            #pragma unroll
            for (int u = 0; u < KNN; u++)
                if (u < t && sel[u] == c) taken = true;
            if (taken) continue;
            const int ci = c / nw, cj = c - (c / nw) * nw;
            const int dy = (ri - ci) * 5, dx = (rj - cj) * 5;
            const int d2 = dy * dy + dx * dx;
            const int key = (d2 << 11) | c;
            if (key < bkey) bkey = key;
        }
        #pragma unroll
        for (int off = 32; off > 0; off >>= 1) {
            int ok = __shfl_down(bkey, off);
            if (ok < bkey) bkey = ok;
        }
        bkey = __shfl(bkey, 0);
        sel[t] = bkey & 2047;
    }
    if (lane < KNN) {
        int c = -1;
        #pragma unroll
        for (int t = 0; t < KNN; t++) if (lane == t) c = sel[t];
        srcCols[r * KNN + lane] = (c > r) ? c : -1;
    }
}

// fused GATv2: logits + softmax + aggregate.
// OM==1: write bf16 only (outb). OM==2: write fp32 (out) AND bf16 (outb).
template<int OM>
__global__ void gat_fused_k(const float* __restrict__ x, int xroff, int xstride,
                            const float* __restrict__ att,
                            const int* __restrict__ srcCols, const float* __restrict__ bias,
                            float* __restrict__ out, unsigned short* __restrict__ outb,
                            int n, int H, int ostride, int ooff)
{
    const int wid = (blockIdx.x * blockDim.x + threadIdx.x) >> 6;
    const int lane = threadIdx.x & 63;
    if (wid >= n * H) return;
    const int h = wid % H;
    const int r = wid / H;
    const int d0 = lane << 2;

    const float4 xrf  = *(const float4*)(x + (size_t)r * xstride + xroff + h * 256 + d0);
    const float4 attf = *(const float4*)(att + (size_t)h * 256 + d0);

    int srcs[8];
    #pragma unroll
    for (int s_ = 0; s_ < KNN; s_++) srcs[s_] = srcCols[r * KNN + s_];
    srcs[7] = r;

    float4 xlf[8];
    float  e[8];
    #pragma unroll
    for (int s_ = 0; s_ < 8; s_++) {
        const int c = srcs[s_];
        float4 v = {0.f, 0.f, 0.f, 0.f};
        if (c >= 0) v = *(const float4*)(x + (size_t)c * xstride + h * 256 + d0);
        xlf[s_] = v;
        float m, p = 0.f;
        m = v.x + xrf.x; m = (m > 0.f) ? m : 0.2f * m; p += m * attf.x;
        m = v.y + xrf.y; m = (m > 0.f) ? m : 0.2f * m; p += m * attf.y;
        m = v.z + xrf.z; m = (m > 0.f) ? m : 0.2f * m; p += m * attf.z;
        m = v.w + xrf.w; m = (m > 0.f) ? m : 0.2f * m; p += m * attf.w;
        #pragma unroll
        for (int off = 32; off > 0; off >>= 1) p += __shfl_down(p, off);
        e[s_] = __shfl(p, 0);
    }

    float mx = e[7];
    #pragma unroll
    for (int s_ = 0; s_ < KNN; s_++)
        if (srcs[s_] >= 0) mx = fmaxf(mx, e[s_]);
    float a[8], denom = 0.f;
    #pragma unroll
    for (int s_ = 0; s_ < 8; s_++) {
        a[s_] = (s_ == 7 || srcs[s_] >= 0) ? expf(e[s_] - mx) : 0.f;
        denom += a[s_];
    }
    const float inv = 1.f / (denom + 1e-16f);

    float o0 = 0.f, o1 = 0.f, o2 = 0.f, o3 = 0.f;
    #pragma unroll
    for (int s_ = 0; s_ < 8; s_++) {
        const float al = a[s_] * inv;
        o0 = fmaf(al, xlf[s_].x, o0); o1 = fmaf(al, xlf[s_].y, o1);
        o2 = fmaf(al, xlf[s_].z, o2); o3 = fmaf(al, xlf[s_].w, o3);
    }
    const float* bb = bias + (size_t)h * 256 + d0;
    o0 += bb[0]; o1 += bb[1]; o2 += bb[2]; o3 += bb[3];
    o0 = (o0 > 0.f) ? o0 : (expf(o0) - 1.f);
    o1 = (o1 > 0.f) ? o1 : (expf(o1) - 1.f);
    o2 = (o2 > 0.f) ? o2 : (expf(o2) - 1.f);
    o3 = (o3 > 0.f) ? o3 : (expf(o3) - 1.f);
    const size_t oi = (size_t)r * ostride + ooff + (size_t)h * 256 + d0;
    if (OM == 2) {
        float4 res = {o0, o1, o2, o3};
        *(float4*)(out + oi) = res;
    }
    ushort4 rb;
    rb.x = f2bf(o0); rb.y = f2bf(o1); rb.z = f2bf(o2); rb.w = f2bf(o3);
    *(ushort4*)(outb + oi) = rb;
}

// ============================ orchestration ============================
static void run_level(void* const* d_in, float* ws, int l, int H, hipStream_t s)
{
    const float* f = (const float*)d_in[l];
    const int nh = H / 5, nw = nh, n = nh * nw;

    const float* convT_w = (const float*)d_in[6]  + (size_t)l * 1638400;
    const float* convT_b = (const float*)d_in[7]  + l * 256;
    const float* conv1_w = (const float*)d_in[8]  + (size_t)l * 1638400;
    const float* conv1_b = (const float*)d_in[9]  + l * 256;
    const float* fc2_w   = (const float*)d_in[10] + (size_t)l * 65536;
    const float* fc2_b   = (const float*)d_in[11] + l * 256;
    const float* fc3_w   = (const float*)d_in[12] + (size_t)l * 131072;
    const float* fc3_b   = (const float*)d_in[13] + l * 256;
    const float* g1_wl   = (const float*)d_in[14] + (size_t)l * 524288;
    const float* g1_bl   = (const float*)d_in[15] + l * 2048;
    const float* g1_wr   = (const float*)d_in[16] + (size_t)l * 524288;
    const float* g1_br   = (const float*)d_in[17] + l * 2048;
    const float* g1_att  = (const float*)d_in[18] + l * 2048;
    const float* g1_bias = (const float*)d_in[19] + l * 2048;
    const float* g2_wl   = (const float*)d_in[20] + (size_t)l * 524288;
    const float* g2_bl   = (const float*)d_in[21] + l * 256;
    const float* g2_wr   = (const float*)d_in[22] + (size_t)l * 524288;
    const float* g2_br   = (const float*)d_in[23] + l * 256;
    const float* g2_att  = (const float*)d_in[24] + l * 256;
    const float* g2_bias = (const float*)d_in[25] + l * 256;
    const float* g3_wl   = (const float*)d_in[26] + (size_t)l * 524288;
    const float* g3_bl   = (const float*)d_in[27] + l * 2048;
    const float* g3_wr   = (const float*)d_in[28] + (size_t)l * 524288;
    const float* g3_br   = (const float*)d_in[29] + l * 2048;
    const float* g3_att  = (const float*)d_in[30] + l * 2048;
    const float* g3_bias = (const float*)d_in[31] + l * 2048;
    const float* g4_wl   = (const float*)d_in[32] + (size_t)l * 524288;
    const float* g4_bl   = (const float*)d_in[33] + l * 256;
    const float* g4_wr   = (const float*)d_in[34] + (size_t)l * 524288;
    const float* g4_br   = (const float*)d_in[35] + l * 256;
    const float* g4_att  = (const float*)d_in[36] + l * 256;
    const float* g4_bias = (const float*)d_in[37] + l * 256;

    float* xs    = ws + (l == 0 ? OFF_XS0 : OFF_XS1);
    float* score = ws + OFF_LAST;
    float* xlr   = ws + OFF_XL;        // [n][4096] fused xl|xr (g1/g3); conv1/fc2 partials
    float* xlr2  = ws + OFF_XL2;       // [n][512]  fused xl|xr (g2/g4)
    float* cat   = ws + OFF_CAT;       // fp32 (Dmat for fc3)
    int* srcF = (int*)(ws + OFF_SRCF);
    int* srcS = (int*)(ws + OFF_SRCS);
    unsigned short* bw   = (unsigned short*)(ws + OFF_BF_W);
    unsigned short* h1b  = (unsigned short*)(ws + OFF_H1);    // [n][2048] bf16
    unsigned short* catb = (unsigned short*)(ws + OFF_BF_A);  // [n][512]  bf16
    unsigned short* hcb  = (unsigned short*)(ws + OFF_HC);    // [n][256]  bf16
    float* part = ws + OFF_ARENA;      // split-K partials

    // ---- conv1 patch embedding via split-precision bf16 MFMA (hi/lo) ----
    unsigned short* Ahi = (unsigned short*)(ws + OFF_ARENA);
    unsigned short* Alo = Ahi + (size_t)n * 6400;
    unsigned short* Whi = (unsigned short*)(ws + OFF_BF_A);
    unsigned short* Wlo = Whi + 1638400;
    unsigned short* embHi = (unsigned short*)(ws + OFF_EMB2);
    unsigned short* embLo = embHi + (size_t)n * 256;
    unsigned short* e2hi  = (unsigned short*)(ws + OFF_EMB);
    unsigned short* e2lo  = e2hi + (size_t)n * 256;

    { int tot = n * 6400;
      extract_patches_hilo_k<<<dim3((tot + 255) / 256), dim3(256), 0, s>>>(f, Ahi, Alo, nw, H, tot); }
    cast_hilo_k<<<dim3((1638400 / 4 + 255) / 256), dim3(256), 0, s>>>(conv1_w, Whi, Wlo, 1638400);
    const int S3 = (l == 0) ? 4 : 8;
    const int Kc1 = ((6400 / S3 + 63) / 64) * 64;
    { dim3 g(2, (n + 127) / 128, 3 * S3);
      bgemm_hilo_sk_k<<<g, dim3(256), 0, s>>>(Ahi, Alo, Whi, Wlo, xlr, n, 256, 6400, Kc1, S3); }
    { const int MN = n * 256;
      bsk_reduce_k<1, false, true, 2><<<dim3((MN / 4 + 255) / 256), dim3(256), 0, s>>>(
          xlr, conv1_b, conv1_b, 256, nullptr, 0, nullptr, embHi, embLo, MN, 256, 3 * S3); }

    // ---- fc2 = relu(emb @ fc2_w^T + b) via hilo MFMA -> e2hi/e2lo ----
    cast_hilo_k<<<dim3((65536 / 4 + 255) / 256), dim3(256), 0, s>>>(fc2_w, bw, bw + 65536, 65536);
    { dim3 g(2, (n + 127) / 128, 3);
      bgemm_hilo_sk_k<<<g, dim3(256), 0, s>>>(embHi, embLo, bw, bw + 65536, xlr, n, 256, 256, 256, 1); }
    { const int MN = n * 256;
      bsk_reduce_k<1, false, true, 2><<<dim3((MN / 4 + 255) / 256), dim3(256), 0, s>>>(
          xlr, fc2_b, fc2_b, 256, nullptr, 0, nullptr, e2hi, e2lo, MN, 256, 3); }

    // ---- score = emb2 @ emb2^T via hilo MFMA ----
    { dim3 g((n + 127) / 128, (n + 127) / 128, 3);
      bgemm_hilo_sk_k<<<g, dim3(256), 0, s>>>(e2hi, e2lo, e2hi, e2lo, part, n, n, 256, 256, 1); }
    { const int MN = n * n;
      bsk_reduce_k<0, false, false, 0><<<dim3((MN / 4 + 255) / 256), dim3(256), 0, s>>>(
          part, nullptr, nullptr, 0, nullptr, 0, score, nullptr, nullptr, MN, n, 3); }

    topk_feat_k<<<dim3(n), dim3(64), 0, s>>>(score, srcF, n);
    topk_spatial_k<<<dim3(n), dim3(64), 0, s>>>(srcS, n, nw);

    const int gatw1 = n * 8;
    const int gatw2 = n;

    // g1: feature graph, emb2 -> h1b [n,2048] bf16, heads=8
    cast_t2(s, g1_wl, g1_wr, bw, bw + 2048 * 256, 256, 2048);
    if (n >= 1024)
        bgemm<BT_NT, 0, 1, false>(s, e2hi, bw, g1_bl, g1_br, 2048, nullptr, 0, xlr, n, 4096, 256);
    else
        bgemm_sk<0, false>(s, e2hi, bw, g1_bl, g1_br, 2048, nullptr, 0, xlr, part, n, 4096, 256, 2);
    gat_fused_k<1><<<dim3((gatw1 + 3) / 4), dim3(256), 0, s>>>(
        xlr, 2048, 4096, g1_att, srcF, g1_bias, nullptr, h1b, n, 8, 2048, 0);

    // g2: feature graph, h1b -> cat[:, :256] (fp32 + bf16), heads=1 (split-K 8)
    cast_t2(s, g2_wl, g2_wr, bw, bw + 256 * 2048, 2048, 256);
    bgemm_sk<0, false>(s, h1b, bw, g2_bl, g2_br, 256, nullptr, 0, xlr2, part, n, 512, 2048, 8);
    gat_fused_k<2><<<dim3((gatw2 + 3) / 4), dim3(256), 0, s>>>(
        xlr2, 256, 512, g2_att, srcF, g2_bias, cat, catb, n, 1, 512, 0);

    // g3: spatial graph, emb2 -> h1b, heads=8
    cast_t2(s, g3_wl, g3_wr, bw, bw + 2048 * 256, 256, 2048);
    if (n >= 1024)
        bgemm<BT_NT, 0, 1, false>(s, e2hi, bw, g3_bl, g3_br, 2048, nullptr, 0, xlr, n, 4096, 256);
    else
        bgemm_sk<0, false>(s, e2hi, bw, g3_bl, g3_br, 2048, nullptr, 0, xlr, part, n, 4096, 256, 2);
    gat_fused_k<1><<<dim3((gatw1 + 3) / 4), dim3(256), 0, s>>>(
        xlr, 2048, 4096, g3_att, srcS, g3_bias, nullptr, h1b, n, 8, 2048, 0);

    // g4: spatial graph, h1b -> cat[:, 256:] (fp32 + bf16), heads=1
    cast_t2(s, g4_wl, g4_wr, bw, bw + 256 * 2048, 2048, 256);
    bgemm_sk<0, false>(s, h1b, bw, g4_bl, g4_br, 256, nullptr, 0, xlr2, part, n, 512, 2048, 8);
    gat_fused_k<2><<<dim3((gatw2 + 3) / 4), dim3(256), 0, s>>>(
        xlr2, 256, 512, g4_att, srcS, g4_bias, cat, catb, n, 1, 512, 256);

    // hc = relu(catb @ fc3_w^T + fc3_b) + cat[:,256:]  -> bf16 hcb (split-K 4)
    cast_bf(s, fc3_w, bw, 131072);
    { dim3 g(2, (n + 127) / 128, 4);
      bgemm_sk_k<<<g, dim3(256), 0, s>>>(catb, bw, part, n, 256, 512, 128); }
    { const int MN = n * 256;
      bsk_reduce_k<1, true, true, 1><<<dim3((MN / 4 + 255) / 256), dim3(256), 0, s>>>(
          part, fc3_b, fc3_b, 256, cat + 256, 512, nullptr, hcb, nullptr, MN, 256, 4); }

    // convT: fused GEMM + scatter epilogue -> xs = f + relu(U + b)
    cast_t(s, convT_w, bw, 256, 6400);
    bgemm_convT(s, hcb, bw, f, convT_b, xs, n, nw, H);
}

extern "C" void kernel_launch(void* const* d_in, const int* in_sizes, int n_in,
                              void* d_out, int out_size, void* d_ws, size_t ws_size,
                              hipStream_t stream)
{
    float* ws  = (float*)d_ws;
    float* out = (float*)d_out;

    run_level(d_in, ws, 0, 200, stream);
    run_level(d_in, ws, 1, 100, stream);

    const float* inner_w = (const float*)d_in[2];
    const float* inner_b = (const float*)d_in[3];
    const float* layer_w = (const float*)d_in[4];
    const float* layer_b = (const float*)d_in[5];
    float* xs0    = ws + OFF_XS0;
    float* xs1    = ws + OFF_XS1;
    float* last   = ws + OFF_LAST;
    float* inner0 = ws + OFF_ARENA;
    unsigned short* bimg = (unsigned short*)(ws + OFF_XL);               // bf16 img (padded for 3x3)
    unsigned short* bw1  = (unsigned short*)(ws + OFF_BF_W);             // 1x1 weights
    unsigned short* bwc  = (unsigned short*)(ws + OFF_BF_W + 100000);    // conv3x3 reordered

    // ---- level 1: last = conv1x1(xs1); out1 = conv3x3(last) ----
    cast_t(stream, xs1, bimg, 256, 10000);
    cast_bf(stream, inner_w + 65536, bw1, 65536);
    bgemm<BT_NT, 0, 0, false>(stream, bw1, bimg, inner_b + 256, nullptr, 0, nullptr, 0,
                              last, 256, 10000, 256);
    reorder_w3_k<<<dim3((589824 + 255) / 256), dim3(256), 0, stream>>>(layer_w + 589824, bwc);
    cast_t_pad(stream, last, nullptr, bimg, 10000, 100, 0);
    bgemm<BT_CONV2, 0, 0, false>(stream, bwc, bimg, layer_b + 256, nullptr, 0, nullptr, 0,
                                 out + 10240000, 256, 10000, 2304, 100, 100);

    // ---- level 0: inner0 = conv1x1(xs0); pad-cast fuses +nearest(last); out0 = conv3x3 ----
    cast_t(stream, xs0, bimg, 256, 40000);
    cast_bf(stream, inner_w, bw1, 65536);
    bgemm<BT_NT, 0, 0, false>(stream, bw1, bimg, inner_b, nullptr, 0, nullptr, 0,
                              inner0, 256, 40000, 256);
    reorder_w3_k<<<dim3((589824 + 255) / 256), dim3(256), 0, stream>>>(layer_w, bwc);
    cast_t_pad(stream, inner0, last, bimg, 40000, 200, 100);
    bgemm<BT_CONV2, 0, 0, false>(stream, bwc, bimg, layer_b, nullptr, 0, nullptr, 0,
                                 out, 256, 40000, 2304, 200, 200);
}

// Round 8
// 1053.977 us; speedup vs baseline: 1.0594x; 1.0445x over previous
//
#include <hip/hip_runtime.h>
#include <cstdint>
#include <cstddef>
#include <math.h>

#define KNN 7

using short8  = __attribute__((ext_vector_type(8))) short;
using floatx4 = __attribute__((ext_vector_type(4))) float;

// ---------------- workspace layout (in floats) ----------------
static const size_t OFF_ARENA = 0;          // 10,240,000  patch hi/lo bf16 / split-K partials / U
static const size_t OFF_XS0   = 10240000;   // 10,240,000
static const size_t OFF_XS1   = 20480000;   //  2,560,000
static const size_t OFF_LAST  = 23040000;   //  2,560,000  score (GNN) / last (FPN)
static const size_t OFF_EMB   = 25600000;   //    409,600  e2hi|e2lo bf16
static const size_t OFF_EMB2  = 26009600;   //    409,600  embHi|embLo bf16
static const size_t OFF_XL    = 26419200;   //  6,553,600 xlr / hilo-splitK part / FPN bf16 img
static const size_t OFF_H1    = 32972800;   //  3,276,800  h1 bf16
static const size_t OFF_XL2   = 36249600;   //    819,200 (xlr2)
static const size_t OFF_CAT   = 37068800;   //    819,200  cat fp32
static const size_t OFF_HC    = 37888000;   //    409,600  hc bf16
static const size_t OFF_SRCF  = 38400000;   //     11,200 ints
static const size_t OFF_SRCS  = 38411200;   //     11,200 ints
static const size_t OFF_BF_A  = 38422400;   //  1,700,000 floats (conv1 W hi+lo / cat bf16)
static const size_t OFF_BF_W  = 40122400;   //    850,000 floats (W casts)
// total ~164 MB

static __device__ __forceinline__ unsigned short f2bf(float f) {
    union { float f; unsigned u; } v; v.f = f;
    unsigned u = v.u;
    unsigned r = u + 0x7fffu + ((u >> 16) & 1u);   // RNE
    return (unsigned short)(r >> 16);
}

static __device__ __forceinline__ float bf2f(unsigned short h) {
    union { unsigned u; float f; } v; v.u = ((unsigned)h) << 16; return v.f;
}

// async global->LDS, 16B per lane. LDS dest is wave-uniform base + lane*16.
static __device__ __forceinline__ void glds16(const void* g, void* l) {
    __builtin_amdgcn_global_load_lds((const __attribute__((address_space(1))) void*)g,
                                     (__attribute__((address_space(3))) void*)l, 16, 0, 0);
}

// ============================ bf16 MFMA GEMM ======
// Hybrid pipelines (both counted-vmcnt, both-sides swizzle, glds-staged):
//  - BT_NT:    BK=64, 2 LDS buffers (64 KB), vmcnt(8).
//  - BT_CONV2: BK=32, 3 LDS buffers (48 KB -> 3 blocks/CU), vmcnt(4),
//              stage-before-compute (2-phase slack). Proven structure.
// BT_CONV2: 3x3 SAME conv; B = ZERO-PADDED bf16 image [(imH+2)(imW+2)][256];
//           A = weights [O][j*256+c]. Border taps read zeros from the ring.
// OOB rows CLAMPED (not zero-filled): epilogue never writes OOB rows/cols.
// NOTE (R7 lesson): do NOT fuse scatter epilogues whose index permutes the
// tile layout — partial-line scattered writes amplified traffic 2.5-3.4x.
enum { BT_NT = 0, BT_CONV2 = 2 };

template<int BT, int ACT, int BAX, bool ADDMAT>
__global__ __launch_bounds__(256)
void bgemm_k(const unsigned short* __restrict__ A, const unsigned short* __restrict__ B,
             const float* __restrict__ bias, const float* __restrict__ bias2, int nsplit,
             const float* __restrict__ Dmat, int Dld,
             float* __restrict__ C, int M, int N, int K, int imH, int imW)
{
    constexpr int LDS_SH = (BT == BT_CONV2) ? 3 * 4096 : 2 * 8192;
    __shared__ unsigned short As[LDS_SH];
    __shared__ unsigned short Bs[LDS_SH];
    const int tid  = threadIdx.x;
    const int lane = tid & 63;
    const int wid  = tid >> 6;
    const int quad = lane >> 4;
    const int l15  = lane & 15;
    const int wy = wid >> 1, wx = wid & 1;

    // block-id swizzle (gridDim.y==2 shapes: conv + 1x1): XCD-chunked bijective.
    int bxx = blockIdx.x, byy = blockIdx.y;
    if (gridDim.y == 2) {
        const int nbx = gridDim.x;
        const int nwg = nbx * 2;
        const int hw  = byy * nbx + bxx;
        const int q = nwg >> 3, r = nwg & 7;
        const int x8 = hw & 7, d = hw >> 3;
        const int lg = (x8 < r) ? x8 * (q + 1) + d : r * (q + 1) + (x8 - r) * q + d;
        byy = lg & 1; bxx = lg >> 1;
    }
    const int bm0 = byy * 128;
    const int bn0 = bxx * 128;

    floatx4 zero = {0.f, 0.f, 0.f, 0.f};
    floatx4 acc[4][4];
    #pragma unroll
    for (int i = 0; i < 4; i++)
        #pragma unroll
        for (int j = 0; j < 4; j++) acc[i][j] = zero;

    if constexpr (BT == BT_CONV2) {
        // ---------- BK=32, 3-buffer pipeline ----------
        const int l4 = lane >> 2;
        const int swc = (((lane & 3) ^ ((lane >> 3) & 3)) << 3);   // shorts
        const int r0 = wid * 32 + l4;
        const int r1 = r0 + 16;
        int am0 = bm0 + r0; if (am0 > M - 1) am0 = M - 1;
        int am1 = bm0 + r1; if (am1 > M - 1) am1 = M - 1;
        const unsigned short* aP0 = A + (size_t)am0 * K + swc;
        const unsigned short* aP1 = A + (size_t)am1 * K + swc;
        const int W2 = imW + 2;
        int pp0 = bn0 + r0; if (pp0 > N - 1) pp0 = N - 1;
        int pp1 = bn0 + r1; if (pp1 > N - 1) pp1 = N - 1;
        const int py0 = pp0 / imW, px0 = pp0 - py0 * imW;
        const int py1 = pp1 / imW, px1 = pp1 - py1 * imW;
        const unsigned short* bP0 = B + ((size_t)(py0 + 1) * W2 + px0 + 1) * 256 + swc;
        const unsigned short* bP1 = B + ((size_t)(py1 + 1) * W2 + px1 + 1) * 256 + swc;

        auto stage = [&](int buf, int t) {
            const int k0 = t << 5;
            glds16(aP0 + k0, &As[buf * 4096 + wid * 1024]);
            glds16(aP1 + k0, &As[buf * 4096 + wid * 1024 + 512]);
            const int jj = k0 >> 8;              // tap 0..8 (uniform scalar)
            const int j3 = jj / 3;
            const ptrdiff_t toff = (ptrdiff_t)((j3 - 1) * W2 + (jj - j3 * 3 - 1)) * 256
                                 + (k0 & 255);
            glds16(bP0 + toff, &Bs[buf * 4096 + wid * 1024]);
            glds16(bP1 + toff, &Bs[buf * 4096 + wid * 1024 + 512]);
        };
        const int rsw = ((quad ^ ((l15 >> 1) & 3)) << 3);   // shorts
        auto compute = [&](int buf) {
            short8 af[4], bfr[4];
            #pragma unroll
            for (int i = 0; i < 4; i++)
                af[i] = *(const short8*)&As[buf * 4096 + (wy * 64 + i * 16 + l15) * 32 + rsw];
            #pragma unroll
            for (int j = 0; j < 4; j++)
                bfr[j] = *(const short8*)&Bs[buf * 4096 + (wx * 64 + j * 16 + l15) * 32 + rsw];
            #pragma unroll
            for (int i = 0; i < 4; i++)
                #pragma unroll
                for (int j = 0; j < 4; j++)
                    acc[i][j] = __builtin_amdgcn_mfma_f32_16x16x32_bf16(af[i], bfr[j], acc[i][j], 0, 0, 0);
        };

        const int T = K >> 5;
        stage(0, 0);
        if (T > 1) stage(1, 1);
        int cb = 0, sb = 2;
        for (int t = 0; t < T; t++) {
            if (t < T - 1) asm volatile("s_waitcnt vmcnt(4) lgkmcnt(0)" ::: "memory");
            else           asm volatile("s_waitcnt vmcnt(0) lgkmcnt(0)" ::: "memory");
            __builtin_amdgcn_s_barrier();
            __builtin_amdgcn_sched_barrier(0);
            if (t + 2 < T) stage(sb, t + 2);
            compute(cb);
            cb = (cb == 2) ? 0 : cb + 1;
            sb = (sb == 2) ? 0 : sb + 1;
        }
    } else {
        // ---------- BK=64, 2-buffer pipeline ----------
        const int l8 = lane >> 3;
        const int swq = (((lane & 7) ^ (l8 & 7)) << 3);   // swizzled source chunk
        const unsigned short* aP[4];
        const unsigned short* bP[4];
        #pragma unroll
        for (int g = 0; g < 4; g++) {
            int ra = bm0 + wid * 32 + g * 8 + l8;
            if (ra > M - 1) ra = M - 1;
            aP[g] = A + (size_t)ra * K + swq;
            int rb = bn0 + wid * 32 + g * 8 + l8;
            if (rb > N - 1) rb = N - 1;
            bP[g] = B + (size_t)rb * K + swq;
        }

        auto stage = [&](int buf, int t) {
            const int k0 = t << 6;
            #pragma unroll
            for (int g = 0; g < 4; g++)
                glds16(aP[g] + k0, &As[buf * 8192 + wid * 2048 + g * 512]);
            #pragma unroll
            for (int g = 0; g < 4; g++)
                glds16(bP[g] + k0, &Bs[buf * 8192 + wid * 2048 + g * 512]);
        };
        auto compute = [&](int buf) {
            #pragma unroll
            for (int ks = 0; ks < 2; ks++) {
                short8 af[4], bfr[4];
                #pragma unroll
                for (int i = 0; i < 4; i++)
                    af[i] = *(const short8*)&As[buf * 8192 + (wy * 64 + i * 16 + l15) * 64
                                                + (((ks * 4 + quad) ^ (l15 & 7)) << 3)];
                #pragma unroll
                for (int j = 0; j < 4; j++)
                    bfr[j] = *(const short8*)&Bs[buf * 8192 + (wx * 64 + j * 16 + l15) * 64
                                                 + (((ks * 4 + quad) ^ (l15 & 7)) << 3)];
                #pragma unroll
                for (int i = 0; i < 4; i++)
                    #pragma unroll
                    for (int j = 0; j < 4; j++)
                        acc[i][j] = __builtin_amdgcn_mfma_f32_16x16x32_bf16(af[i], bfr[j], acc[i][j], 0, 0, 0);
            }
        };

        const int T2 = K >> 6;
        stage(0, 0);
        if (T2 > 1) stage(1, 1);
        for (int t = 0; t < T2; t++) {
            if (t + 1 < T2) asm volatile("s_waitcnt vmcnt(8) lgkmcnt(0)" ::: "memory");
            else            asm volatile("s_waitcnt vmcnt(0) lgkmcnt(0)" ::: "memory");
            __builtin_amdgcn_s_barrier();
            __builtin_amdgcn_sched_barrier(0);
            compute(t & 1);
            __builtin_amdgcn_s_barrier();
            __builtin_amdgcn_sched_barrier(0);
            if (t + 2 < T2) stage(t & 1, t + 2);
        }
    }

    #pragma unroll
    for (int i = 0; i < 4; i++) {
        #pragma unroll
        for (int r = 0; r < 4; r++) {
            const int m = bm0 + wy * 64 + i * 16 + quad * 4 + r;
            if (m >= M) continue;
            #pragma unroll
            for (int j = 0; j < 4; j++) {
                const int n = bn0 + wx * 64 + j * 16 + l15;
                if (n >= N) continue;
                float v = acc[i][j][r];
                if (bias != nullptr)
                    v += (BAX == 0) ? bias[m] : (n < nsplit ? bias[n] : bias2[n - nsplit]);
                if (ACT == 1) v = fmaxf(v, 0.f);
                if (ADDMAT) v += Dmat[(size_t)m * Dld + n];
                C[(size_t)m * N + n] = v;
            }
        }
    }
}

template<int BT, int ACT, int BAX, bool ADDMAT>
static inline void bgemm(hipStream_t s, const unsigned short* A, const unsigned short* B,
                         const float* bias, const float* bias2, int nsplit,
                         const float* D, int Dld, float* C,
                         int M, int N, int K, int imH = 0, int imW = 0)
{
    dim3 g((N + 127) / 128, (M + 127) / 128);
    bgemm_k<BT, ACT, BAX, ADDMAT><<<g, dim3(256), 0, s>>>(A, B, bias, bias2, nsplit,
                                                          D, Dld, C, M, N, K, imH, imW);
}

// ---- bf16 split-K (NT only): partials fp32; BK=64 pipeline ----
__global__ __launch_bounds__(256)
void bgemm_sk_k(const unsigned short* __restrict__ A, const unsigned short* __restrict__ B,
                float* __restrict__ part, int M, int N, int K, int Kc)
{
    __shared__ unsigned short As[2][8192];
    __shared__ unsigned short Bs[2][8192];
    const int tid  = threadIdx.x;
    const int lane = tid & 63;
    const int wid  = tid >> 6;
    const int quad = lane >> 4;
    const int l15  = lane & 15;
    const int l8   = lane >> 3;
    const int wy = wid >> 1, wx = wid & 1;
    const int bm0 = blockIdx.y * 128;
    const int bn0 = blockIdx.x * 128;
    const int kbeg = blockIdx.z * Kc;
    const int kend = (kbeg + Kc < K) ? kbeg + Kc : K;

    floatx4 zero = {0.f, 0.f, 0.f, 0.f};
    floatx4 acc[4][4];
    #pragma unroll
    for (int i = 0; i < 4; i++)
        #pragma unroll
        for (int j = 0; j < 4; j++) acc[i][j] = zero;

    const int swq = (((lane & 7) ^ (l8 & 7)) << 3);
    const unsigned short* aP[4];
    const unsigned short* bP[4];
    #pragma unroll
    for (int g = 0; g < 4; g++) {
        int ra = bm0 + wid * 32 + g * 8 + l8;
        if (ra > M - 1) ra = M - 1;
        aP[g] = A + (size_t)ra * K + kbeg + swq;
        int rb = bn0 + wid * 32 + g * 8 + l8;
        if (rb > N - 1) rb = N - 1;
        bP[g] = B + (size_t)rb * K + kbeg + swq;
    }

    auto stage = [&](int buf, int t) {
        const int k0 = t << 6;
        #pragma unroll
        for (int g = 0; g < 4; g++)
            glds16(aP[g] + k0, &As[buf][wid * 2048 + g * 512]);
        #pragma unroll
        for (int g = 0; g < 4; g++)
            glds16(bP[g] + k0, &Bs[buf][wid * 2048 + g * 512]);
    };
    auto compute = [&](int buf) {
        #pragma unroll
        for (int ks = 0; ks < 2; ks++) {
            short8 af[4], bfr[4];
            #pragma unroll
            for (int i = 0; i < 4; i++)
                af[i] = *(const short8*)&As[buf][(wy * 64 + i * 16 + l15) * 64
                                                 + (((ks * 4 + quad) ^ (l15 & 7)) << 3)];
            #pragma unroll
            for (int j = 0; j < 4; j++)
                bfr[j] = *(const short8*)&Bs[buf][(wx * 64 + j * 16 + l15) * 64
                                                  + (((ks * 4 + quad) ^ (l15 & 7)) << 3)];
            #pragma unroll
            for (int i = 0; i < 4; i++)
                #pragma unroll
                for (int j = 0; j < 4; j++)
                    acc[i][j] = __builtin_amdgcn_mfma_f32_16x16x32_bf16(af[i], bfr[j], acc[i][j], 0, 0, 0);
        }
    };

    const int T2 = (kend - kbeg) >> 6;
    stage(0, 0);
    if (T2 > 1) stage(1, 1);
    for (int t = 0; t < T2; t++) {
        if (t + 1 < T2) asm volatile("s_waitcnt vmcnt(8) lgkmcnt(0)" ::: "memory");
        else            asm volatile("s_waitcnt vmcnt(0) lgkmcnt(0)" ::: "memory");
        __builtin_amdgcn_s_barrier();
        __builtin_amdgcn_sched_barrier(0);
        compute(t & 1);
        __builtin_amdgcn_s_barrier();
        __builtin_amdgcn_sched_barrier(0);
        if (t + 2 < T2) stage(t & 1, t + 2);
    }

    float* P = part + (size_t)blockIdx.z * M * N;
    #pragma unroll
    for (int i = 0; i < 4; i++) {
        #pragma unroll
        for (int r = 0; r < 4; r++) {
            const int m = bm0 + wy * 64 + i * 16 + quad * 4 + r;
            if (m >= M) continue;
            #pragma unroll
            for (int j = 0; j < 4; j++) {
                const int n = bn0 + wx * 64 + j * 16 + l15;
                if (n >= N) continue;
                P[(size_t)m * N + n] = acc[i][j][r];
            }
        }
    }
}

// ---- split-precision (hi/lo bf16) fp32-emulating split-K GEMM ----
// C = A*B as Ahi*Bhi + Alo*Bhi + Ahi*Blo (missing lo*lo ~ 2^-18).
// blockIdx.z = seg * S3 + slab. Slab lengths must be %64 == 0.
__global__ __launch_bounds__(256)
void bgemm_hilo_sk_k(const unsigned short* __restrict__ Ahi, const unsigned short* __restrict__ Alo,
                     const unsigned short* __restrict__ Bhi, const unsigned short* __restrict__ Blo,
                     float* __restrict__ part, int M, int N, int K, int Kc, int S3)
{
    __shared__ unsigned short As[2][8192];
    __shared__ unsigned short Bs[2][8192];
    const int tid  = threadIdx.x;
    const int lane = tid & 63;
    const int wid  = tid >> 6;
    const int quad = lane >> 4;
    const int l15  = lane & 15;
    const int l8   = lane >> 3;
    const int wy = wid >> 1, wx = wid & 1;
    const int bm0 = blockIdx.y * 128;
    const int bn0 = blockIdx.x * 128;

    const int seg  = blockIdx.z / S3;
    const int slab = blockIdx.z - seg * S3;
    const unsigned short* A = (seg == 1) ? Alo : Ahi;
    const unsigned short* B = (seg == 2) ? Blo : Bhi;
    const int kbeg = slab * Kc;
    const int kend = (kbeg + Kc < K) ? kbeg + Kc : K;

    floatx4 zero = {0.f, 0.f, 0.f, 0.f};
    floatx4 acc[4][4];
    #pragma unroll
    for (int i = 0; i < 4; i++)
        #pragma unroll
        for (int j = 0; j < 4; j++) acc[i][j] = zero;

    const int swq = (((lane & 7) ^ (l8 & 7)) << 3);
    const unsigned short* aP[4];
    const unsigned short* bP[4];
    #pragma unroll
    for (int g = 0; g < 4; g++) {
        int ra = bm0 + wid * 32 + g * 8 + l8;
        if (ra > M - 1) ra = M - 1;
        aP[g] = A + (size_t)ra * K + kbeg + swq;
        int rb = bn0 + wid * 32 + g * 8 + l8;
        if (rb > N - 1) rb = N - 1;
        bP[g] = B + (size_t)rb * K + kbeg + swq;
    }

    auto stage = [&](int buf, int t) {
        const int k0 = t << 6;
        #pragma unroll
        for (int g = 0; g < 4; g++)
            glds16(aP[g] + k0, &As[buf][wid * 2048 + g * 512]);
        #pragma unroll
        for (int g = 0; g < 4; g++)
            glds16(bP[g] + k0, &Bs[buf][wid * 2048 + g * 512]);
    };
    auto compute = [&](int buf) {
        #pragma unroll
        for (int ks = 0; ks < 2; ks++) {
            short8 af[4], bfr[4];
            #pragma unroll
            for (int i = 0; i < 4; i++)
                af[i] = *(const short8*)&As[buf][(wy * 64 + i * 16 + l15) * 64
                                                 + (((ks * 4 + quad) ^ (l15 & 7)) << 3)];
            #pragma unroll
            for (int j = 0; j < 4; j++)
                bfr[j] = *(const short8*)&Bs[buf][(wx * 64 + j * 16 + l15) * 64
                                                  + (((ks * 4 + quad) ^ (l15 & 7)) << 3)];
            #pragma unroll
            for (int i = 0; i < 4; i++)
                #pragma unroll
                for (int j = 0; j < 4; j++)
                    acc[i][j] = __builtin_amdgcn_mfma_f32_16x16x32_bf16(af[i], bfr[j], acc[i][j], 0, 0, 0);
        }
    };

    const int T2 = (kend - kbeg) >> 6;
    stage(0, 0);
    if (T2 > 1) stage(1, 1);
    for (int t = 0; t < T2; t++) {
        if (t + 1 < T2) asm volatile("s_waitcnt vmcnt(8) lgkmcnt(0)" ::: "memory");
        else            asm volatile("s_waitcnt vmcnt(0) lgkmcnt(0)" ::: "memory");
        __builtin_amdgcn_s_barrier();
        __builtin_amdgcn_sched_barrier(0);
        compute(t & 1);
        __builtin_amdgcn_s_barrier();
        __builtin_amdgcn_sched_barrier(0);
        if (t + 2 < T2) stage(t & 1, t + 2);
    }

    float* P = part + (size_t)blockIdx.z * M * N;
    #pragma unroll
    for (int i = 0; i < 4; i++) {
        #pragma unroll
        for (int r = 0; r < 4; r++) {
            const int m = bm0 + wy * 64 + i * 16 + quad * 4 + r;
            if (m >= M) continue;
            #pragma unroll
            for (int j = 0; j < 4; j++) {
                const int n = bn0 + wx * 64 + j * 16 + l15;
                if (n >= N) continue;
                P[(size_t)m * N + n] = acc[i][j][r];
            }
        }
    }
}

// reduce S slabs + optional dual-bias(axis n) + relu + addmat.
// OUT: 0 = fp32 C; 1 = bf16 Chi; 2 = hi/lo bf16 pair (Chi, Clo).
template<int ACT, bool ADDMAT, bool BIAS, int OUT>
__global__ void bsk_reduce_k(const float* __restrict__ part,
                             const float* __restrict__ bias, const float* __restrict__ bias2,
                             int nsplit, const float* __restrict__ Dmat, int Dld,
                             float* __restrict__ C, unsigned short* __restrict__ Chi,
                             unsigned short* __restrict__ Clo,
                             int MN, int N, int S)
{
    const int i4 = (blockIdx.x * 256 + threadIdx.x) * 4;
    if (i4 >= MN) return;
    float4 a = *(const float4*)(part + i4);
    for (int s = 1; s < S; s++) {
        const float4 b = *(const float4*)(part + (size_t)s * MN + i4);
        a.x += b.x; a.y += b.y; a.z += b.z; a.w += b.w;
    }
    const int n = i4 % N;
    if (BIAS) {
        const float* bb = (n < nsplit) ? (bias + n) : (bias2 + n - nsplit);
        a.x += bb[0]; a.y += bb[1]; a.z += bb[2]; a.w += bb[3];
    }
    if (ACT == 1) {
        a.x = fmaxf(a.x, 0.f); a.y = fmaxf(a.y, 0.f);
        a.z = fmaxf(a.z, 0.f); a.w = fmaxf(a.w, 0.f);
    }
    if (ADDMAT) {
        const int m = i4 / N;
        const float4 d = *(const float4*)(Dmat + (size_t)m * Dld + n);
        a.x += d.x; a.y += d.y; a.z += d.z; a.w += d.w;
    }
    if (OUT == 0) {
        *(float4*)(C + i4) = a;
    } else if (OUT == 1) {
        ushort4 h;
        h.x = f2bf(a.x); h.y = f2bf(a.y); h.z = f2bf(a.z); h.w = f2bf(a.w);
        *(ushort4*)(Chi + i4) = h;
    } else {
        ushort4 h, l;
        h.x = f2bf(a.x); l.x = f2bf(a.x - bf2f(h.x));
        h.y = f2bf(a.y); l.y = f2bf(a.y - bf2f(h.y));
        h.z = f2bf(a.z); l.z = f2bf(a.z - bf2f(h.z));
        h.w = f2bf(a.w); l.w = f2bf(a.w - bf2f(h.w));
        *(ushort4*)(Chi + i4) = h;
        *(ushort4*)(Clo + i4) = l;
    }
}

template<int ACT, bool ADDMAT>
static inline void bgemm_sk(hipStream_t s, const unsigned short* A, const unsigned short* B,
                            const float* bias, const float* bias2, int nsplit,
                            const float* D, int Dld, float* C, float* part,
                            int M, int N, int K, int S)
{
    const int Kc = ((K / S + 63) / 64) * 64;
    dim3 g((N + 127) / 128, (M + 127) / 128, S);
    bgemm_sk_k<<<g, dim3(256), 0, s>>>(A, B, part, M, N, K, Kc);
    const int MN = M * N;
    bsk_reduce_k<ACT, ADDMAT, true, 0><<<dim3((MN / 4 + 255) / 256), dim3(256), 0, s>>>(
        part, bias, bias2, nsplit, D, Dld, C, nullptr, nullptr, MN, N, S);
}

// ============================ cast / reorder kernels ============================
__global__ void cast_bf16_k(const float* __restrict__ in, unsigned short* __restrict__ out, int total)
{
    const int i4 = (blockIdx.x * 256 + threadIdx.x) * 4;
    if (i4 + 4 <= total) {
        const float4 v = *(const float4*)(in + i4);
        ushort4 o;
        o.x = f2bf(v.x); o.y = f2bf(v.y); o.z = f2bf(v.z); o.w = f2bf(v.w);
        *(ushort4*)(out + i4) = o;
    } else {
        for (int i = i4; i < total; i++) out[i] = f2bf(in[i]);
    }
}

static inline void cast_bf(hipStream_t s, const float* in, unsigned short* out, int total)
{
    cast_bf16_k<<<dim3((total / 4 + 255) / 256), dim3(256), 0, s>>>(in, out, total);
}

// elementwise hi/lo split cast
__global__ void cast_hilo_k(const float* __restrict__ in, unsigned short* __restrict__ hi,
                            unsigned short* __restrict__ lo, int total)
{
    const int i4 = (blockIdx.x * 256 + threadIdx.x) * 4;
    if (i4 + 4 <= total) {
        const float4 v = *(const float4*)(in + i4);
        ushort4 h, l;
        h.x = f2bf(v.x); l.x = f2bf(v.x - bf2f(h.x));
        h.y = f2bf(v.y); l.y = f2bf(v.y - bf2f(h.y));
        h.z = f2bf(v.z); l.z = f2bf(v.z - bf2f(h.z));
        h.w = f2bf(v.w); l.w = f2bf(v.w - bf2f(h.w));
        *(ushort4*)(hi + i4) = h;
        *(ushort4*)(lo + i4) = l;
    } else {
        for (int i = i4; i < total; i++) {
            unsigned short h = f2bf(in[i]);
            hi[i] = h; lo[i] = f2bf(in[i] - bf2f(h));
        }
    }
}

__device__ __forceinline__ void cast_t_body(const float* __restrict__ in,
                                            unsigned short* __restrict__ out, int K, int N)
{
    __shared__ float tile[64][65];
    const int n0 = blockIdx.x * 64;
    const int k0 = blockIdx.y * 64;
    const int t = threadIdx.x;
    const int r = t >> 2;
    const int c4 = (t & 3) << 4;
    {
        const int k = k0 + r;
        if (k < K && n0 + c4 + 16 <= N) {
            const float4* p = (const float4*)(in + (size_t)k * N + n0 + c4);
            *(float4*)&tile[r][c4]      = p[0];
            *(float4*)&tile[r][c4 + 4]  = p[1];
            *(float4*)&tile[r][c4 + 8]  = p[2];
            *(float4*)&tile[r][c4 + 12] = p[3];
        } else {
            for (int i = 0; i < 16; i++)
                tile[r][c4 + i] = (k < K && n0 + c4 + i < N) ? in[(size_t)k * N + n0 + c4 + i] : 0.f;
        }
    }
    __syncthreads();
    const int n = n0 + r;
    if (n >= N) return;
    unsigned short tmp[16];
    #pragma unroll
    for (int i = 0; i < 16; i++) tmp[i] = f2bf(tile[c4 + i][r]);
    if (k0 + 64 <= K) {
        *(uint4*)(out + (size_t)n * K + k0 + c4)     = *(uint4*)&tmp[0];
        *(uint4*)(out + (size_t)n * K + k0 + c4 + 8) = *(uint4*)&tmp[8];
    } else {
        for (int i = 0; i < 16; i++)
            if (k0 + c4 + i < K) out[(size_t)n * K + k0 + c4 + i] = tmp[i];
    }
}

__global__ void cast_t_k(const float* __restrict__ in, unsigned short* __restrict__ out, int K, int N)
{
    cast_t_body(in, out, K, N);
}

__global__ void cast_t2_k(const float* __restrict__ in0, const float* __restrict__ in1,
                          unsigned short* __restrict__ out0, unsigned short* __restrict__ out1,
                          int K, int N)
{
    if (blockIdx.z == 0) cast_t_body(in0, out0, K, N);
    else                 cast_t_body(in1, out1, K, N);
}

static inline void cast_t(hipStream_t s, const float* in, unsigned short* out, int K, int N)
{
    cast_t_k<<<dim3((N + 63) / 64, (K + 63) / 64), dim3(256), 0, s>>>(in, out, K, N);
}

static inline void cast_t2(hipStream_t s, const float* in0, const float* in1,
                           unsigned short* out0, unsigned short* out1, int K, int N)
{
    cast_t2_k<<<dim3((N + 63) / 64, (K + 63) / 64, 2), dim3(256), 0, s>>>(in0, in1, out0, out1, K, N);
}

// transpose-cast [256][N] fp32 -> ZERO-PADDED bf16 image [(imH+2)(imW+2)][256]
// grid.y==4 plane zeroes the border ring; planes 0..3 are K-chunks.
// optional fused nearest-2x upsample-add: + up[c][py>>1][px>>1]
__global__ void cast_t_pad_k(const float* __restrict__ in, const float* __restrict__ up,
                             unsigned short* __restrict__ out, int N, int imW, int upW)
{
    if (blockIdx.y == 4) {           // border ring zeroing
        const int imH = N / imW;
        const int W2 = imW + 2;
        const int nb = 2 * W2 + 2 * imH;
        const int idx = blockIdx.x * 256 + threadIdx.x;
        if (idx >= nb * 32) return;
        const int p = idx >> 5;
        const int c8 = (idx & 31) << 3;
        int row;
        if (p < W2)            row = p;
        else if (p < 2 * W2)   row = (imH + 1) * W2 + (p - W2);
        else { const int q = p - 2 * W2; const int y = q >> 1;
               row = (y + 1) * W2 + ((q & 1) ? (imW + 1) : 0); }
        *(uint4*)(out + (size_t)row * 256 + c8) = (uint4){0, 0, 0, 0};
        return;
    }
    __shared__ float tile[64][65];
    const int n0 = blockIdx.x * 64;
    const int k0 = blockIdx.y * 64;   // 0..3 * 64, K = 256
    const int t = threadIdx.x;
    const int r = t >> 2;
    const int c4 = (t & 3) << 4;
    {
        const int k = k0 + r;
        if (n0 + c4 + 16 <= N) {
            const float4* p = (const float4*)(in + (size_t)k * N + n0 + c4);
            *(float4*)&tile[r][c4]      = p[0];
            *(float4*)&tile[r][c4 + 4]  = p[1];
            *(float4*)&tile[r][c4 + 8]  = p[2];
            *(float4*)&tile[r][c4 + 12] = p[3];
        } else {
            for (int i = 0; i < 16; i++)
                tile[r][c4 + i] = (n0 + c4 + i < N) ? in[(size_t)k * N + n0 + c4 + i] : 0.f;
        }
    }
    __syncthreads();
    const int n = n0 + r;
    if (n >= N) return;
    const int py = n / imW, px = n - py * imW;
    unsigned short tmp[16];
    if (up != nullptr) {
        const float* u = up + (size_t)(py >> 1) * upW + (px >> 1);
        #pragma unroll
        for (int i = 0; i < 16; i++)
            tmp[i] = f2bf(tile[c4 + i][r] + u[(size_t)(k0 + c4 + i) * upW * upW]);
    } else {
        #pragma unroll
        for (int i = 0; i < 16; i++) tmp[i] = f2bf(tile[c4 + i][r]);
    }
    unsigned short* o = out + ((size_t)(py + 1) * (imW + 2) + px + 1) * 256 + k0 + c4;
    *(uint4*)(o)     = *(uint4*)&tmp[0];
    *(uint4*)(o + 8) = *(uint4*)&tmp[8];
}

static inline void cast_t_pad(hipStream_t s, const float* in, const float* up,
                              unsigned short* out, int N, int imW, int upW)
{
    cast_t_pad_k<<<dim3((N + 63) / 64, 5), dim3(256), 0, s>>>(in, up, out, N, imW, upW);
}

__global__ void reorder_w3_k(const float* __restrict__ in, unsigned short* __restrict__ out)
{
    const int idx = blockIdx.x * 256 + threadIdx.x;
    if (idx >= 589824) return;
    const int o = idx / 2304;
    const int r = idx - o * 2304;
    const int j = r >> 8;
    const int c = r & 255;
    out[idx] = f2bf(in[(size_t)o * 2304 + c * 9 + j]);
}

// ============================ small kernels ============================
// extract patches directly into hi/lo bf16 A-matrices [n][6400]
__global__ void extract_patches_hilo_k(const float* __restrict__ f,
                                       unsigned short* __restrict__ hi,
                                       unsigned short* __restrict__ lo,
                                       int nw, int H, int total)
{
    int idx = blockIdx.x * 256 + threadIdx.x;
    if (idx >= total) return;
    int q = idx % 6400;
    int p = idx / 6400;
    int c = q / 25;
    int rem = q - c * 25;
    int a = rem / 5, b = rem - (rem / 5) * 5;
    int ih = p / nw, iw = p - (p / nw) * nw;
    const float v = f[(size_t)c * H * H + (size_t)(ih * 5 + a) * H + (iw * 5 + b)];
    const unsigned short h = f2bf(v);
    hi[idx] = h;
    lo[idx] = f2bf(v - bf2f(h));
}

__global__ void topk_feat_k(const float* __restrict__ score, int* __restrict__ srcCols, int n)
{
    const int r = blockIdx.x;
    const int lane = threadIdx.x;
    const float* row = score + (size_t)r * n;
    int   sel[KNN];
    float selv[KNN];
    #pragma unroll
    for (int t = 0; t < KNN; t++) {
        float best = -__builtin_huge_valf();
        int   bidx = 0x7fffffff;
        for (int c = lane; c < n; c += 64) {
            bool taken = false;
            #pragma unroll
            for (int u = 0; u < KNN; u++)
                if (u < t && sel[u] == c) taken = true;
            if (taken) continue;
            float v = row[c];
            if (v > best || (v == best && c < bidx)) { best = v; bidx = c; }
        }
        #pragma unroll
        for (int off = 32; off > 0; off >>= 1) {
            float ov = __shfl_down(best, off);
            int   oi = __shfl_down(bidx, off);
            if (ov > best || (ov == best && oi < bidx)) { best = ov; bidx = oi; }
        }
        best = __shfl(best, 0);
        bidx = __shfl(bidx, 0);
        sel[t] = bidx; selv[t] = best;
    }
    if (lane < KNN) {
        int c = -1; float v = 0.f;
        #pragma unroll
        for (int t = 0; t < KNN; t++)
            if (lane == t) { c = sel[t]; v = selv[t]; }
        srcCols[r * KNN + lane] = (c > r && v != 0.0f) ? c : -1;
    }
}

__global__ void topk_spatial_k(int* __restrict__ srcCols, int n, int nw)
{
    const int r = blockIdx.x;
    const int lane = threadIdx.x;
    const int ri = r / nw, rj = r - (r / nw) * nw;
    int sel[KNN];
    #pragma unroll
    for (int t = 0; t < KNN; t++) {
        int bkey = 0x7fffffff;
        for (int c = lane; c < n; c += 64) {
            bool taken = false;
            #pragma unroll
            for (int u = 0; u < KNN; u++)
                if (u < t && sel[u] == c) taken = true;
            if (taken) continue;
            const int ci = c / nw, cj = c - (c / nw) * nw;
            const int dy = (ri - ci) * 5, dx = (rj - cj) * 5;
            const int d2 = dy * dy + dx * dx;
            const int key = (d2 << 11) | c;
            if (key < bkey) bkey = key;
        }
        #pragma unroll
        for (int off = 32; off > 0; off >>= 1) {
            int ok = __shfl_down(bkey, off);
            if (ok < bkey) bkey = ok;
        }
        bkey = __shfl(bkey, 0);
        sel[t] = bkey & 2047;
    }
    if (lane < KNN) {
        int c = -1;
        #pragma unroll
        for (int t = 0; t < KNN; t++) if (lane == t) c = sel[t];
        srcCols[r * KNN + lane] = (c > r) ? c : -1;
    }
}

// fused GATv2: logits + softmax + aggregate.
// OM==1: write bf16 only (outb). OM==2: write fp32 (out) AND bf16 (outb).
template<int OM>
__global__ void gat_fused_k(const float* __restrict__ x, int xroff, int xstride,
                            const float* __restrict__ att,
                            const int* __restrict__ srcCols, const float* __restrict__ bias,
                            float* __restrict__ out, unsigned short* __restrict__ outb,
                            int n, int H, int ostride, int ooff)
{
    const int wid = (blockIdx.x * blockDim.x + threadIdx.x) >> 6;
    const int lane = threadIdx.x & 63;
    if (wid >= n * H) return;
    const int h = wid % H;
    const int r = wid / H;
    const int d0 = lane << 2;

    const float4 xrf  = *(const float4*)(x + (size_t)r * xstride + xroff + h * 256 + d0);
    const float4 attf = *(const float4*)(att + (size_t)h * 256 + d0);

    int srcs[8];
    #pragma unroll
    for (int s_ = 0; s_ < KNN; s_++) srcs[s_] = srcCols[r * KNN + s_];
    srcs[7] = r;

    float4 xlf[8];
    float  e[8];
    #pragma unroll
    for (int s_ = 0; s_ < 8; s_++) {
        const int c = srcs[s_];
        float4 v = {0.f, 0.f, 0.f, 0.f};
        if (c >= 0) v = *(const float4*)(x + (size_t)c * xstride + h * 256 + d0);
        xlf[s_] = v;
        float m, p = 0.f;
        m = v.x + xrf.x; m = (m > 0.f) ? m : 0.2f * m; p += m * attf.x;
        m = v.y + xrf.y; m = (m > 0.f) ? m : 0.2f * m; p += m * attf.y;
        m = v.z + xrf.z; m = (m > 0.f) ? m : 0.2f * m; p += m * attf.z;
        m = v.w + xrf.w; m = (m > 0.f) ? m : 0.2f * m; p += m * attf.w;
        #pragma unroll
        for (int off = 32; off > 0; off >>= 1) p += __shfl_down(p, off);
        e[s_] = __shfl(p, 0);
    }

    float mx = e[7];
    #pragma unroll
    for (int s_ = 0; s_ < KNN; s_++)
        if (srcs[s_] >= 0) mx = fmaxf(mx, e[s_]);
    float a[8], denom = 0.f;
    #pragma unroll
    for (int s_ = 0; s_ < 8; s_++) {
        a[s_] = (s_ == 7 || srcs[s_] >= 0) ? expf(e[s_] - mx) : 0.f;
        denom += a[s_];
    }
    const float inv = 1.f / (denom + 1e-16f);

    float o0 = 0.f, o1 = 0.f, o2 = 0.f, o3 = 0.f;
    #pragma unroll
    for (int s_ = 0; s_ < 8; s_++) {
        const float al = a[s_] * inv;
        o0 = fmaf(al, xlf[s_].x, o0); o1 = fmaf(al, xlf[s_].y, o1);
        o2 = fmaf(al, xlf[s_].z, o2); o3 = fmaf(al, xlf[s_].w, o3);
    }
    const float* bb = bias + (size_t)h * 256 + d0;
    o0 += bb[0]; o1 += bb[1]; o2 += bb[2]; o3 += bb[3];
    o0 = (o0 > 0.f) ? o0 : (expf(o0) - 1.f);
    o1 = (o1 > 0.f) ? o1 : (expf(o1) - 1.f);
    o2 = (o2 > 0.f) ? o2 : (expf(o2) - 1.f);
    o3 = (o3 > 0.f) ? o3 : (expf(o3) - 1.f);
    const size_t oi = (size_t)r * ostride + ooff + (size_t)h * 256 + d0;
    if (OM == 2) {
        float4 res = {o0, o1, o2, o3};
        *(float4*)(out + oi) = res;
    }
    ushort4 rb;
    rb.x = f2bf(o0); rb.y = f2bf(o1); rb.z = f2bf(o2); rb.w = f2bf(o3);
    *(ushort4*)(outb + oi) = rb;
}

__global__ void scatter_convT_k(const float* __restrict__ f, const float* __restrict__ U,
                                const float* __restrict__ bias, float* __restrict__ xs,
                                int nw, int H, int total)
{
    int idx = blockIdx.x * 256 + threadIdx.x;
    if (idx >= total) return;
    int x = idx % H;
    int t = idx / H;
    int y = t % H;
    int o = t / H;
    int j = y / 5, a = y - j * 5;
    int i = x / 5, b = x - i * 5;
    int p = i * nw + j;
    float v = U[(size_t)p * 6400 + o * 25 + a * 5 + b] + bias[o];
    v = fmaxf(v, 0.f);
    xs[idx] = f[idx] + v;
}

// ============================ orchestration ============================
static void run_level(void* const* d_in, float* ws, int l, int H, hipStream_t s)
{
    const float* f = (const float*)d_in[l];
    const int nh = H / 5, nw = nh, n = nh * nw, HW = H * H;

    const float* convT_w = (const float*)d_in[6]  + (size_t)l * 1638400;
    const float* convT_b = (const float*)d_in[7]  + l * 256;
    const float* conv1_w = (const float*)d_in[8]  + (size_t)l * 1638400;
    const float* conv1_b = (const float*)d_in[9]  + l * 256;
    const float* fc2_w   = (const float*)d_in[10] + (size_t)l * 65536;
    const float* fc2_b   = (const float*)d_in[11] + l * 256;
    const float* fc3_w   = (const float*)d_in[12] + (size_t)l * 131072;
    const float* fc3_b   = (const float*)d_in[13] + l * 256;
    const float* g1_wl   = (const float*)d_in[14] + (size_t)l * 524288;
    const float* g1_bl   = (const float*)d_in[15] + l * 2048;
    const float* g1_wr   = (const float*)d_in[16] + (size_t)l * 524288;
    const float* g1_br   = (const float*)d_in[17] + l * 2048;
    const float* g1_att  = (const float*)d_in[18] + l * 2048;
    const float* g1_bias = (const float*)d_in[19] + l * 2048;
    const float* g2_wl   = (const float*)d_in[20] + (size_t)l * 524288;
    const float* g2_bl   = (const float*)d_in[21] + l * 256;
    const float* g2_wr   = (const float*)d_in[22] + (size_t)l * 524288;
    const float* g2_br   = (const float*)d_in[23] + l * 256;
    const float* g2_att  = (const float*)d_in[24] + l * 256;
    const float* g2_bias = (const float*)d_in[25] + l * 256;
    const float* g3_wl   = (const float*)d_in[26] + (size_t)l * 524288;
    const float* g3_bl   = (const float*)d_in[27] + l * 2048;
    const float* g3_wr   = (const float*)d_in[28] + (size_t)l * 524288;
    const float* g3_br   = (const float*)d_in[29] + l * 2048;
    const float* g3_att  = (const float*)d_in[30] + l * 2048;
    const float* g3_bias = (const float*)d_in[31] + l * 2048;
    const float* g4_wl   = (const float*)d_in[32] + (size_t)l * 524288;
    const float* g4_bl   = (const float*)d_in[33] + l * 256;
    const float* g4_wr   = (const float*)d_in[34] + (size_t)l * 524288;
    const float* g4_br   = (const float*)d_in[35] + l * 256;
    const float* g4_att  = (const float*)d_in[36] + l * 256;
    const float* g4_bias = (const float*)d_in[37] + l * 256;

    float* xs    = ws + (l == 0 ? OFF_XS0 : OFF_XS1);
    float* score = ws + OFF_LAST;
    float* xlr   = ws + OFF_XL;        // [n][4096] fused xl|xr (g1/g3); conv1/fc2 partials
    float* xlr2  = ws + OFF_XL2;       // [n][512]  fused xl|xr (g2/g4)
    float* cat   = ws + OFF_CAT;       // fp32 (Dmat for fc3)
    int* srcF = (int*)(ws + OFF_SRCF);
    int* srcS = (int*)(ws + OFF_SRCS);
    unsigned short* bw   = (unsigned short*)(ws + OFF_BF_W);
    unsigned short* h1b  = (unsigned short*)(ws + OFF_H1);    // [n][2048] bf16
    unsigned short* catb = (unsigned short*)(ws + OFF_BF_A);  // [n][512]  bf16
    unsigned short* hcb  = (unsigned short*)(ws + OFF_HC);    // [n][256]  bf16
    float* part = ws + OFF_ARENA;      // split-K partials / U (convT)
    float* patches = ws + OFF_ARENA;

    // ---- conv1 patch embedding via split-precision bf16 MFMA (hi/lo) ----
    unsigned short* Ahi = (unsigned short*)(ws + OFF_ARENA);
    unsigned short* Alo = Ahi + (size_t)n * 6400;
    unsigned short* Whi = (unsigned short*)(ws + OFF_BF_A);
    unsigned short* Wlo = Whi + 1638400;
    unsigned short* embHi = (unsigned short*)(ws + OFF_EMB2);
    unsigned short* embLo = embHi + (size_t)n * 256;
    unsigned short* e2hi  = (unsigned short*)(ws + OFF_EMB);
    unsigned short* e2lo  = e2hi + (size_t)n * 256;

    { int tot = n * 6400;
      extract_patches_hilo_k<<<dim3((tot + 255) / 256), dim3(256), 0, s>>>(f, Ahi, Alo, nw, H, tot); }
    cast_hilo_k<<<dim3((1638400 / 4 + 255) / 256), dim3(256), 0, s>>>(conv1_w, Whi, Wlo, 1638400);
    const int S3 = (l == 0) ? 4 : 8;
    const int Kc1 = ((6400 / S3 + 63) / 64) * 64;
    { dim3 g(2, (n + 127) / 128, 3 * S3);
      bgemm_hilo_sk_k<<<g, dim3(256), 0, s>>>(Ahi, Alo, Whi, Wlo, xlr, n, 256, 6400, Kc1, S3); }
    { const int MN = n * 256;
      bsk_reduce_k<1, false, true, 2><<<dim3((MN / 4 + 255) / 256), dim3(256), 0, s>>>(
          xlr, conv1_b, conv1_b, 256, nullptr, 0, nullptr, embHi, embLo, MN, 256, 3 * S3); }

    // ---- fc2 = relu(emb @ fc2_w^T + b) via hilo MFMA -> e2hi/e2lo ----
    cast_hilo_k<<<dim3((65536 / 4 + 255) / 256), dim3(256), 0, s>>>(fc2_w, bw, bw + 65536, 65536);
    { dim3 g(2, (n + 127) / 128, 3);
      bgemm_hilo_sk_k<<<g, dim3(256), 0, s>>>(embHi, embLo, bw, bw + 65536, xlr, n, 256, 256, 256, 1); }
    { const int MN = n * 256;
      bsk_reduce_k<1, false, true, 2><<<dim3((MN / 4 + 255) / 256), dim3(256), 0, s>>>(
          xlr, fc2_b, fc2_b, 256, nullptr, 0, nullptr, e2hi, e2lo, MN, 256, 3); }

    // ---- score = emb2 @ emb2^T via hilo MFMA ----
    { dim3 g((n + 127) / 128, (n + 127) / 128, 3);
      bgemm_hilo_sk_k<<<g, dim3(256), 0, s>>>(e2hi, e2lo, e2hi, e2lo, part, n, n, 256, 256, 1); }
    { const int MN = n * n;
      bsk_reduce_k<0, false, false, 0><<<dim3((MN / 4 + 255) / 256), dim3(256), 0, s>>>(
          part, nullptr, nullptr, 0, nullptr, 0, score, nullptr, nullptr, MN, n, 3); }

    topk_feat_k<<<dim3(n), dim3(64), 0, s>>>(score, srcF, n);
    topk_spatial_k<<<dim3(n), dim3(64), 0, s>>>(srcS, n, nw);

    const int gatw1 = n * 8;
    const int gatw2 = n;

    // g1: feature graph, emb2 -> h1b [n,2048] bf16, heads=8
    cast_t2(s, g1_wl, g1_wr, bw, bw + 2048 * 256, 256, 2048);
    if (n >= 1024)
        bgemm<BT_NT, 0, 1, false>(s, e2hi, bw, g1_bl, g1_br, 2048, nullptr, 0, xlr, n, 4096, 256);
    else
        bgemm_sk<0, false>(s, e2hi, bw, g1_bl, g1_br, 2048, nullptr, 0, xlr, part, n, 4096, 256, 2);
    gat_fused_k<1><<<dim3((gatw1 + 3) / 4), dim3(256), 0, s>>>(
        xlr, 2048, 4096, g1_att, srcF, g1_bias, nullptr, h1b, n, 8, 2048, 0);

    // g2: feature graph, h1b -> cat[:, :256] (fp32 + bf16), heads=1 (split-K 8)
    cast_t2(s, g2_wl, g2_wr, bw, bw + 256 * 2048, 2048, 256);
    bgemm_sk<0, false>(s, h1b, bw, g2_bl, g2_br, 256, nullptr, 0, xlr2, part, n, 512, 2048, 8);
    gat_fused_k<2><<<dim3((gatw2 + 3) / 4), dim3(256), 0, s>>>(
        xlr2, 256, 512, g2_att, srcF, g2_bias, cat, catb, n, 1, 512, 0);

    // g3: spatial graph, emb2 -> h1b, heads=8
    cast_t2(s, g3_wl, g3_wr, bw, bw + 2048 * 256, 256, 2048);
    if (n >= 1024)
        bgemm<BT_NT, 0, 1, false>(s, e2hi, bw, g3_bl, g3_br, 2048, nullptr, 0, xlr, n, 4096, 256);
    else
        bgemm_sk<0, false>(s, e2hi, bw, g3_bl, g3_br, 2048, nullptr, 0, xlr, part, n, 4096, 256, 2);
    gat_fused_k<1><<<dim3((gatw1 + 3) / 4), dim3(256), 0, s>>>(
        xlr, 2048, 4096, g3_att, srcS, g3_bias, nullptr, h1b, n, 8, 2048, 0);

    // g4: spatial graph, h1b -> cat[:, 256:] (fp32 + bf16), heads=1
    cast_t2(s, g4_wl, g4_wr, bw, bw + 256 * 2048, 2048, 256);
    bgemm_sk<0, false>(s, h1b, bw, g4_bl, g4_br, 256, nullptr, 0, xlr2, part, n, 512, 2048, 8);
    gat_fused_k<2><<<dim3((gatw2 + 3) / 4), dim3(256), 0, s>>>(
        xlr2, 256, 512, g4_att, srcS, g4_bias, cat, catb, n, 1, 512, 256);

    // hc = relu(catb @ fc3_w^T + fc3_b) + cat[:,256:]  -> bf16 hcb (split-K 4)
    cast_bf(s, fc3_w, bw, 131072);
    { dim3 g(2, (n + 127) / 128, 4);
      bgemm_sk_k<<<g, dim3(256), 0, s>>>(catb, bw, part, n, 256, 512, 128); }
    { const int MN = n * 256;
      bsk_reduce_k<1, true, true, 1><<<dim3((MN / 4 + 255) / 256), dim3(256), 0, s>>>(
          part, fc3_b, fc3_b, 256, cat + 256, 512, nullptr, hcb, nullptr, MN, 256, 4); }

    // convT: U = hc @ convT_w (coalesced write), then scatter (coalesced xs write)
    cast_t(s, convT_w, bw, 256, 6400);
    bgemm<BT_NT, 0, 1, false>(s, hcb, bw, nullptr, nullptr, 0, nullptr, 0, patches, n, 6400, 256);
    { int tot = 256 * HW;
      scatter_convT_k<<<dim3((tot + 255) / 256), dim3(256), 0, s>>>(f, patches, convT_b, xs, nw, H, tot); }
}

extern "C" void kernel_launch(void* const* d_in, const int* in_sizes, int n_in,
                              void* d_out, int out_size, void* d_ws, size_t ws_size,
                              hipStream_t stream)
{
    float* ws  = (float*)d_ws;
    float* out = (float*)d_out;

    run_level(d_in, ws, 0, 200, stream);
    run_level(d_in, ws, 1, 100, stream);

    const float* inner_w = (const float*)d_in[2];
    const float* inner_b = (const float*)d_in[3];
    const float* layer_w = (const float*)d_in[4];
    const float* layer_b = (const float*)d_in[5];
    float* xs0    = ws + OFF_XS0;
    float* xs1    = ws + OFF_XS1;
    float* last   = ws + OFF_LAST;
    float* inner0 = ws + OFF_ARENA;
    unsigned short* bimg = (unsigned short*)(ws + OFF_XL);               // bf16 img (padded for 3x3)
    unsigned short* bw1  = (unsigned short*)(ws + OFF_BF_W);             // 1x1 weights
    unsigned short* bwc  = (unsigned short*)(ws + OFF_BF_W + 100000);    // conv3x3 reordered

    // ---- level 1: last = conv1x1(xs1); out1 = conv3x3(last) ----
    cast_t(stream, xs1, bimg, 256, 10000);
    cast_bf(stream, inner_w + 65536, bw1, 65536);
    bgemm<BT_NT, 0, 0, false>(stream, bw1, bimg, inner_b + 256, nullptr, 0, nullptr, 0,
                              last, 256, 10000, 256);
    reorder_w3_k<<<dim3((589824 + 255) / 256), dim3(256), 0, stream>>>(layer_w + 589824, bwc);
    cast_t_pad(stream, last, nullptr, bimg, 10000, 100, 0);
    bgemm<BT_CONV2, 0, 0, false>(stream, bwc, bimg, layer_b + 256, nullptr, 0, nullptr, 0,
                                 out + 10240000, 256, 10000, 2304, 100, 100);

    // ---- level 0: inner0 = conv1x1(xs0); pad-cast fuses +nearest(last); out0 = conv3x3 ----
    cast_t(stream, xs0, bimg, 256, 40000);
    cast_bf(stream, inner_w, bw1, 65536);
    bgemm<BT_NT, 0, 0, false>(stream, bw1, bimg, inner_b, nullptr, 0, nullptr, 0,
                              inner0, 256, 40000, 256);
    reorder_w3_k<<<dim3((589824 + 255) / 256), dim3(256), 0, stream>>>(layer_w, bwc);
    cast_t_pad(stream, inner0, last, bimg, 40000, 200, 100);
    bgemm<BT_CONV2, 0, 0, false>(stream, bwc, bimg, layer_b, nullptr, 0, nullptr, 0,
                                 out, 256, 40000, 2304, 200, 200);
}